// Round 3
// baseline (276.251 us; speedup 1.0000x reference)
//
#include <hip/hip_runtime.h>
#include <stdint.h>

#define BATCH 4
#define SEQ 2048
#define DMODEL 1024
#define NHEADS 16
#define HDIM 64
#define MROWS (BATCH * SEQ)   // 8192

typedef float floatx4 __attribute__((ext_vector_type(4)));
typedef __bf16 bf16x8 __attribute__((ext_vector_type(8)));
typedef __bf16 bf16x4 __attribute__((ext_vector_type(4)));
typedef short short8 __attribute__((ext_vector_type(8)));

__device__ __forceinline__ unsigned short f32_to_bf16(float f) {
    union { float f; unsigned int u; } c; c.f = f;
    unsigned int u = c.u;
    unsigned int r = (u + 0x7FFFu + ((u >> 16) & 1u)) >> 16;
    return (unsigned short)r;
}

// async global->LDS 16B per lane (LDS dest = wave-uniform base + lane*16)
__device__ __forceinline__ void async_ld16(const void* g, void* l) {
    __builtin_amdgcn_global_load_lds(
        (const __attribute__((address_space(1))) unsigned int*)g,
        (__attribute__((address_space(3))) unsigned int*)l, 16, 0, 0);
}

#define BARRIER() do { asm volatile("" ::: "memory"); \
    __builtin_amdgcn_s_barrier(); asm volatile("" ::: "memory"); } while (0)

// ---------------------------------------------------------------- convert x
__global__ __launch_bounds__(256) void conv_f32_bf16(
    const float* __restrict__ in, unsigned short* __restrict__ out, int n4) {
    int i = blockIdx.x * 256 + threadIdx.x;
    if (i < n4) {
        float4 v = ((const float4*)in)[i];
        ushort4 o;
        o.x = f32_to_bf16(v.x); o.y = f32_to_bf16(v.y);
        o.z = f32_to_bf16(v.z); o.w = f32_to_bf16(v.w);
        ((ushort4*)out)[i] = o;
    }
}

// ------------------------------------------- transpose+convert W [K,N] -> [N,K] bf16
__global__ __launch_bounds__(256) void transp_conv(
    const float* __restrict__ in, unsigned short* __restrict__ out, int K, int N) {
    __shared__ float tile[32][33];
    int bx = blockIdx.x * 32;  // n
    int by = blockIdx.y * 32;  // k
    int tx = threadIdx.x, ty = threadIdx.y;
#pragma unroll
    for (int i = 0; i < 4; ++i)
        tile[ty + i * 8][tx] = in[(size_t)(by + ty + i * 8) * N + bx + tx];
    __syncthreads();
#pragma unroll
    for (int i = 0; i < 4; ++i)
        out[(size_t)(bx + ty + i * 8) * K + by + tx] = f32_to_bf16(tile[tx][ty + i * 8]);
}

// --------------- per-head bf16 transpose [T,64] -> [64,T], keys PERMUTED within
// each 64-tile: k2 = (k&15)*4 + (k>>4)&3  (must match attn's packed-P layout)
__global__ __launch_bounds__(256) void transp_bf16_head(
    const unsigned short* __restrict__ in, unsigned short* __restrict__ out) {
    __shared__ unsigned short tile[32][33];
    const unsigned short* src = in + (size_t)blockIdx.z * SEQ * HDIM;
    unsigned short* dst = out + (size_t)blockIdx.z * SEQ * HDIM;
    int bx = blockIdx.x * 32;  // d block
    int by = blockIdx.y * 32;  // t block
    int tx = threadIdx.x, ty = threadIdx.y;
#pragma unroll
    for (int i = 0; i < 4; ++i)
        tile[ty + i * 8][tx] = src[(size_t)(by + ty + i * 8) * HDIM + bx + tx];
    __syncthreads();
#pragma unroll
    for (int i = 0; i < 4; ++i) {
        int keyg = by + tx;
        int col2 = (keyg & ~63) | (((keyg & 15) << 2) | ((keyg >> 4) & 3));
        dst[(size_t)(bx + ty + i * 8) * SEQ + col2] = tile[tx][ty + i * 8];
    }
}

// ---------------------------------------------------------------- GEMM 256x256, 8-phase
// T2+T3+T4+T5 template (learn_hip m201 structure, re-derived):
//  512 thr / 8 waves (2M x 4N), BK=64, LDS 128KB = 2buf x 2half x [128][64] x {A,B}.
//  st_16x32 swizzle: phys = logical ^ ((row>>2&1)<<5 bytes). Staged via pre-swizzled
//  global SOURCE + linear LDS dest (rule #21); read side XORs xle=((l16>>2)&1)*16 elems.
//  Stage unit = 64 rows x 128B = 8KB = 1 gload_lds instr/thread. 8 units/tile.
//  Per tile, 4 phases: {ds_read subtile; stage 2 units; barrier; 16 MFMA (setprio);
//  barrier}. Unit X(t+2) staged exactly one phase after X(t)'s last ds_read:
//    ph1: B64-127(t+1) halves (last read prev tile ph2)   [parity b^1]
//    ph2: A rows0-63 (t+2)   (last read t.ph1)            [parity b]
//    ph3: B rows0-63 (t+2)   (last read t.ph2)
//    ph4: A rows64-127 (t+2) (last read t.ph3)
//  One vmcnt(6) per tile boundary: drains all 8 units of tile t, leaves t+1's
//  first 6 in flight (queue 14 -> 6). vmcnt(0) only entering the last tile.
template <int EPI>
__global__ __launch_bounds__(512, 1) void gemm256(
    const unsigned short* __restrict__ A, const unsigned short* __restrict__ Bt,
    const float* __restrict__ bias, float* __restrict__ Cout,
    unsigned short* __restrict__ Qo, unsigned short* __restrict__ Ko,
    unsigned short* __restrict__ Vo, int M, int N, int K) {
    __shared__ __align__(16) unsigned short ldsA[2][2][8192];  // [buf][half][128*64]
    __shared__ __align__(16) unsigned short ldsB[2][2][8192];

    const int tid = threadIdx.x;
    const int lane = tid & 63;
    const int w = tid >> 6;              // 0..7
    const int wm = w >> 2, wn = w & 3;   // 2 x 4
    const int quad = lane >> 4, l16 = lane & 15;
    const int m0 = blockIdx.y * 256;
    const int n0 = blockIdx.x * 256;
    const int ldb = K * 2;               // row stride bytes (A and Bt)
    const int NT = K >> 6;               // 64-wide K tiles

    // ---- staging source map (st_16x32 pre-swizzle; src row == dest row,
    //      src col = dest col ^ 32B when dest-row bit2 set)
    const int t16 = tid * 16;
    const int soff = t16 ^ (((t16 >> 9) & 1) << 5);
    const int srow = soff >> 7;          // 0..63 within unit
    const int scol = soff & 127;
    const char* pAs = (const char*)A + (size_t)(m0 + srow) * ldb + scol;
    const char* pBs = (const char*)Bt + (size_t)(n0 + srow) * ldb + scol;
    char* ldA0 = (char*)&ldsA[0][0][0] + t16;
    char* ldB0 = (char*)&ldsB[0][0][0] + t16;

    // unit uu = half*2 + rowquarter; LDS byte = buf*32768 + uu*8192 + t16
    auto stA = [&](int kt, int uu) {
        async_ld16(pAs + (size_t)uu * 64 * ldb + kt * 128,
                   ldA0 + ((kt & 1) << 15) + (uu << 13));
    };
    auto stB = [&](int kt, int uu) {
        async_ld16(pBs + (size_t)uu * 64 * ldb + kt * 128,
                   ldB0 + ((kt & 1) << 15) + (uu << 13));
    };

    const int xle = ((l16 >> 2) & 1) << 4;   // element xor (16 elems = 32B)

    floatx4 acc[8][4];
#pragma unroll
    for (int mf = 0; mf < 8; ++mf)
#pragma unroll
        for (int nf = 0; nf < 4; ++nf) acc[mf][nf] = (floatx4){0.f, 0.f, 0.f, 0.f};

    // ---- prologue: tile0 all 8 units, then tile1's first 6 (issue order = drain order)
    stA(0, 0); stA(0, 1); stA(0, 2); stA(0, 3);
    stB(0, 0); stB(0, 1); stB(0, 2); stB(0, 3);
    if (NT > 1) {
        stA(1, 0); stA(1, 2);
        stB(1, 0); stB(1, 2);
        stA(1, 1); stA(1, 3);
    }

#define MFMA16(dst, af, bf) dst = __builtin_amdgcn_mfma_f32_16x16x32_bf16(af, bf, dst, 0, 0, 0)

    for (int t = 0; t < NT; ++t) {
        const int b = t & 1;
        if (t + 1 < NT) asm volatile("s_waitcnt vmcnt(6)" ::: "memory");
        else            asm volatile("s_waitcnt vmcnt(0)" ::: "memory");
        BARRIER();  // tile t fully landed in every wave's LDS slice

        const unsigned short* Ab = &ldsA[b][wm][0];
        const unsigned short* Bb = &ldsB[b][wn >> 1][(wn & 1) * 4096];

        bf16x8 aR[4][2], bR[4][2];

        // ---- phase 1: read A Mf0-3 (8) + B Nf0-1 (4); stage B hi-halves (t+1)
#pragma unroll
        for (int mf = 0; mf < 4; ++mf)
#pragma unroll
            for (int kk = 0; kk < 2; ++kk)
                aR[mf][kk] = *(const bf16x8*)&Ab[(mf * 16 + l16) * 64 +
                                                 ((kk * 32 + quad * 8) ^ xle)];
#pragma unroll
        for (int nf = 0; nf < 2; ++nf)
#pragma unroll
            for (int kk = 0; kk < 2; ++kk)
                bR[nf][kk] = *(const bf16x8*)&Bb[(nf * 16 + l16) * 64 +
                                                 ((kk * 32 + quad * 8) ^ xle)];
        if (t + 1 < NT) { stB(t + 1, 1); stB(t + 1, 3); }
        BARRIER();
        __builtin_amdgcn_s_setprio(1);
#pragma unroll
        for (int mf = 0; mf < 4; ++mf)
#pragma unroll
            for (int nf = 0; nf < 2; ++nf)
#pragma unroll
                for (int kk = 0; kk < 2; ++kk)
                    MFMA16(acc[mf][nf], aR[mf][kk], bR[nf][kk]);
        __builtin_amdgcn_s_setprio(0);
        BARRIER();

        // ---- phase 2: read B Nf2-3 (4); stage A rows0-63 (t+2); MFMA q(0, hi-N)
#pragma unroll
        for (int nf = 2; nf < 4; ++nf)
#pragma unroll
            for (int kk = 0; kk < 2; ++kk)
                bR[nf][kk] = *(const bf16x8*)&Bb[(nf * 16 + l16) * 64 +
                                                 ((kk * 32 + quad * 8) ^ xle)];
        if (t + 2 < NT) { stA(t + 2, 0); stA(t + 2, 2); }
        BARRIER();
        __builtin_amdgcn_s_setprio(1);
#pragma unroll
        for (int mf = 0; mf < 4; ++mf)
#pragma unroll
            for (int nf = 2; nf < 4; ++nf)
#pragma unroll
                for (int kk = 0; kk < 2; ++kk)
                    MFMA16(acc[mf][nf], aR[mf][kk], bR[nf][kk]);
        __builtin_amdgcn_s_setprio(0);
        BARRIER();

        // ---- phase 3: read A Mf4-7 (8); stage B rows0-63 (t+2); MFMA q(1, hi-N)
#pragma unroll
        for (int mf = 0; mf < 4; ++mf)
#pragma unroll
            for (int kk = 0; kk < 2; ++kk)
                aR[mf][kk] = *(const bf16x8*)&Ab[((mf + 4) * 16 + l16) * 64 +
                                                 ((kk * 32 + quad * 8) ^ xle)];
        if (t + 2 < NT) { stB(t + 2, 0); stB(t + 2, 2); }
        BARRIER();
        __builtin_amdgcn_s_setprio(1);
#pragma unroll
        for (int mf = 0; mf < 4; ++mf)
#pragma unroll
            for (int nf = 2; nf < 4; ++nf)
#pragma unroll
                for (int kk = 0; kk < 2; ++kk)
                    MFMA16(acc[mf + 4][nf], aR[mf][kk], bR[nf][kk]);
        __builtin_amdgcn_s_setprio(0);
        BARRIER();

        // ---- phase 4: stage A rows64-127 (t+2); MFMA q(1, lo-N) (B lo kept live)
        if (t + 2 < NT) { stA(t + 2, 1); stA(t + 2, 3); }
        BARRIER();
        __builtin_amdgcn_s_setprio(1);
#pragma unroll
        for (int mf = 0; mf < 4; ++mf)
#pragma unroll
            for (int nf = 0; nf < 2; ++nf)
#pragma unroll
                for (int kk = 0; kk < 2; ++kk)
                    MFMA16(acc[mf + 4][nf], aR[mf][kk], bR[nf][kk]);
        __builtin_amdgcn_s_setprio(0);
        // tile boundary (wait + barrier) at loop top
    }
#undef MFMA16

    // ---- epilogue
#pragma unroll
    for (int mf = 0; mf < 8; ++mf)
#pragma unroll
        for (int nf = 0; nf < 4; ++nf)
#pragma unroll
            for (int r = 0; r < 4; ++r) {
                int m = m0 + wm * 128 + mf * 16 + quad * 4 + r;
                int n = n0 + wn * 64 + nf * 16 + l16;
                float v = acc[mf][nf][r] + bias[n];
                if (EPI == 1) {
                    Cout[(size_t)m * N + n] = v;
                } else {
                    int sel = n >> 10, c = n & 1023;
                    int head = c >> 6, d = c & 63;
                    int bb = m >> 11, tt = m & 2047;
                    unsigned short* dst = sel == 0 ? Qo : (sel == 1 ? Ko : Vo);
                    dst[((((size_t)bb * NHEADS + head) * SEQ + tt) << 6) + d] = f32_to_bf16(v);
                }
            }
}

// ---------------------------------------------------------------- flash attention v9
// Block-shared double-buffered K/V LDS staging via global_load_lds (coalesced 1KB
// DMA per instr, source chunk-swizzled, dest lane-linear). 4 waves/block share one
// bh; strips (sA, 63-sA); block-uniform tile counts (2by+2, 32-2by) = 34 total, so
// barriers never diverge (short waves' extra tiles fully masked -> P=0, harmless).
// Prefetch issued AFTER the barrier so the barrier drain hits landed loads.
// Numerics identical to R8: no-max exp2, packed-P per-wave LDS, MFMA-ones lsum.
__global__ __launch_bounds__(256, 2) void attn_kernel(
    const unsigned short* __restrict__ Qg, const unsigned short* __restrict__ Kg,
    const unsigned short* __restrict__ Vtg, unsigned short* __restrict__ Yatt) {
    __shared__ __align__(16) unsigned short Kb2[2][4096];  // [buf][key][d]   8KB each
    __shared__ __align__(16) unsigned short Vb2[2][4096];  // [buf][d][key~]  8KB each
    __shared__ __align__(16) unsigned short Ps[4][2048];   // per-wave packed P

    const int tid = threadIdx.x;
    const int lane = tid & 63;
    const int w = tid >> 6;
    const int quad = lane >> 4, l16 = lane & 15;
    const int bh = blockIdx.x;           // 0..63 -> XCD bh%8 (L2 locality)
    const int by = blockIdx.y;           // 0..7
    const int sA = by * 4 + w;           // strip 0..31 (mirror = 63-sA)
    const size_t base = (size_t)bh * SEQ * HDIM;
    const int bIdx = bh >> 4, h = bh & 15;
    unsigned short* Pw = &Ps[w][0];
    const float csc = 0.18033688f;  // 0.125 * log2(e)

    const int lrow = lane >> 3;                 // 0..7 within a DMA instr
    const int lch = (lane & 7) ^ lrow;          // source chunk (store-swizzle ^ row&7)

    short8 osv = {0x3F80, 0x3F80, 0x3F80, 0x3F80, 0x3F80, 0x3F80, 0x3F80, 0x3F80};
    bf16x8 ones = __builtin_bit_cast(bf16x8, osv);

    for (int half = 0; half < 2; ++half) {
        const int rowb = (half == 0 ? sA : 63 - sA) * 32;
        const int kmaxB = (half == 0) ? (2 * by + 2) : (32 - 2 * by);  // block-uniform

        // Q fragments -> registers
        bf16x8 qf[2][2];
#pragma unroll
        for (int mt = 0; mt < 2; ++mt)
#pragma unroll
            for (int kk = 0; kk < 2; ++kk)
                qf[mt][kk] = *(const bf16x8*)&Qg[base + (size_t)(rowb + mt * 16 + l16) * 64 +
                                                 kk * 32 + quad * 8];

        floatx4 lsum[2];
        floatx4 o[2][4];
#pragma unroll
        for (int mt = 0; mt < 2; ++mt) {
            lsum[mt] = (floatx4){0.f, 0.f, 0.f, 0.f};
#pragma unroll
            for (int nt = 0; nt < 4; ++nt) o[mt][nt] = (floatx4){0.f, 0.f, 0.f, 0.f};
        }

        // prologue: stage tile 0 into buf 0 (wave's 2+2 DMA instructions)
        // (safe w/o extra barrier: half-0 kmaxB is even, so buf0's last half-0 use
        //  finished before the final half-0 barrier)
        {
            const unsigned short* Ktg = Kg + base;
            const unsigned short* Vtg_t = Vtg + base;
#pragma unroll
            for (int ii = 0; ii < 2; ++ii) {
                int i = w * 2 + ii;
                async_ld16(Ktg + (i * 8 + lrow) * 64 + lch * 8,
                           &Kb2[0][i * 512 + lane * 8]);
                async_ld16(Vtg_t + (size_t)(i * 8 + lrow) * SEQ + lch * 8,
                           &Vb2[0][i * 512 + lane * 8]);
            }
        }

        for (int kb = 0; kb < kmaxB; ++kb) {
            const int b = kb & 1;
            __syncthreads();  // drains own DMA (tile kb landed); syncs buffer reuse

            if (kb + 1 < kmaxB) {  // prefetch AFTER barrier -> survives the drain
                const unsigned short* Ktg = Kg + base + (size_t)(kb + 1) * 64 * HDIM;
                const unsigned short* Vtg_t = Vtg + base + (kb + 1) * 64;
#pragma unroll
                for (int ii = 0; ii < 2; ++ii) {
                    int i = w * 2 + ii;
                    async_ld16(Ktg + (i * 8 + lrow) * 64 + lch * 8,
                               &Kb2[1 - b][i * 512 + lane * 8]);
                    async_ld16(Vtg_t + (size_t)(i * 8 + lrow) * SEQ + lch * 8,
                               &Vb2[1 - b][i * 512 + lane * 8]);
                }
            }

            // S = Q K^T : fragments from LDS (swizzle chunk ^ (l16&7))
            floatx4 s[2][4];
#pragma unroll
            for (int mt = 0; mt < 2; ++mt)
#pragma unroll
                for (int nt = 0; nt < 4; ++nt) s[mt][nt] = (floatx4){0.f, 0.f, 0.f, 0.f};
#pragma unroll
            for (int kk = 0; kk < 2; ++kk) {
                bf16x8 kf[4];
#pragma unroll
                for (int nt = 0; nt < 4; ++nt)
                    kf[nt] = *(const bf16x8*)&Kb2[b][(nt * 16 + l16) * 64 +
                                                     ((kk * 4 + quad) ^ (l16 & 7)) * 8];
#pragma unroll
                for (int nt = 0; nt < 4; ++nt)
#pragma unroll
                    for (int mt = 0; mt < 2; ++mt)
                        s[mt][nt] = __builtin_amdgcn_mfma_f32_16x16x32_bf16(
                            qf[mt][kk], kf[nt], s[mt][nt], 0, 0, 0);
            }

            if ((kb * 64 + 63) > rowb) {  // wave-uniform; also covers extra tiles
#pragma unroll
                for (int mt = 0; mt < 2; ++mt)
#pragma unroll
                    for (int nt = 0; nt < 4; ++nt)
#pragma unroll
                        for (int r = 0; r < 4; ++r) {
                            int key = kb * 64 + nt * 16 + l16;
                            int qrow = rowb + mt * 16 + quad * 4 + r;
                            if (key > qrow) s[mt][nt][r] = -INFINITY;
                        }
            }

            // p = exp2(score * 0.125*log2e) == exp(score/8); no max subtraction
#pragma unroll
            for (int mt = 0; mt < 2; ++mt)
#pragma unroll
                for (int nt = 0; nt < 4; ++nt)
#pragma unroll
                    for (int r = 0; r < 4; ++r)
                        s[mt][nt][r] = __builtin_amdgcn_exp2f(s[mt][nt][r] * csc);

            // P -> per-wave LDS, packed slots k2 = l16*4+nt; swizzled by (prow&14)
#pragma unroll
            for (int mt = 0; mt < 2; ++mt)
#pragma unroll
                for (int r = 0; r < 4; ++r) {
                    int prow = mt * 16 + quad * 4 + r;
                    int unit = l16 ^ (prow & 14);
                    floatx4 t = {s[mt][0][r], s[mt][1][r], s[mt][2][r], s[mt][3][r]};
                    bf16x4 pv = __builtin_convertvector(t, bf16x4);
                    *(bf16x4*)&Pw[prow * 64 + unit * 4] = pv;
                }

            // O += P V ; l += P 1   (V^T pre-permuted to packed key order)
#pragma unroll
            for (int kk = 0; kk < 2; ++kk) {
                bf16x8 af[2];
#pragma unroll
                for (int mt = 0; mt < 2; ++mt) {
                    int prow = mt * 16 + l16;
                    int u2 = (kk * 8 + quad * 2) ^ (l16 & 14);
                    af[mt] = *(const bf16x8*)&Pw[prow * 64 + u2 * 4];
                }
#pragma unroll
                for (int nt = 0; nt < 4; ++nt) {
                    bf16x8 vf = *(const bf16x8*)&Vb2[b][(nt * 16 + l16) * 64 +
                                                        ((kk * 4 + quad) ^ (l16 & 7)) * 8];
#pragma unroll
                    for (int mt = 0; mt < 2; ++mt)
                        o[mt][nt] = __builtin_amdgcn_mfma_f32_16x16x32_bf16(
                            af[mt], vf, o[mt][nt], 0, 0, 0);
                }
#pragma unroll
                for (int mt = 0; mt < 2; ++mt)
                    lsum[mt] = __builtin_amdgcn_mfma_f32_16x16x32_bf16(
                        af[mt], ones, lsum[mt], 0, 0, 0);
            }
        }

#pragma unroll
        for (int mt = 0; mt < 2; ++mt)
#pragma unroll
            for (int r = 0; r < 4; ++r) {
                float inv = 1.0f / lsum[mt][r];
                int qrow = rowb + mt * 16 + quad * 4 + r;
#pragma unroll
                for (int nt = 0; nt < 4; ++nt)
                    Yatt[((size_t)(bIdx * SEQ + qrow) << 10) + h * 64 + nt * 16 + l16] =
                        f32_to_bf16(o[mt][nt][r] * inv);
            }
    }
}

// ---------------------------------------------------------------- launch
extern "C" void kernel_launch(void* const* d_in, const int* in_sizes, int n_in,
                              void* d_out, int out_size, void* d_ws, size_t ws_size,
                              hipStream_t stream) {
    const float* x = (const float*)d_in[0];
    const float* w_qkv = (const float*)d_in[1];
    const float* b_qkv = (const float*)d_in[2];
    const float* w_proj = (const float*)d_in[3];
    const float* b_proj = (const float*)d_in[4];
    float* out = (float*)d_out;

    char* ws = (char*)d_ws;
    unsigned short* xb     = (unsigned short*)(ws);                       // 16 MB
    unsigned short* wqkvT  = (unsigned short*)(ws + 16777216);            // 6 MB
    unsigned short* wprojT = (unsigned short*)(ws + 23068672);            // 2 MB
    unsigned short* Qb     = (unsigned short*)(ws + 25165824);            // 16 MB
    unsigned short* Kb     = (unsigned short*)(ws + 41943040);            // 16 MB
    unsigned short* Vb     = (unsigned short*)(ws + 58720256);            // 16 MB
    unsigned short* Yatt   = (unsigned short*)(ws + 75497472);            // 16 MB
    unsigned short* Vt     = (unsigned short*)(ws + 92274688);            // 16 MB

    conv_f32_bf16<<<8192, 256, 0, stream>>>(x, xb, (MROWS * DMODEL) / 4);
    transp_conv<<<dim3(96, 32), dim3(32, 8), 0, stream>>>(w_qkv, wqkvT, DMODEL, 3 * DMODEL);
    transp_conv<<<dim3(32, 32), dim3(32, 8), 0, stream>>>(w_proj, wprojT, DMODEL, DMODEL);
    gemm256<0><<<dim3(12, 32), 512, 0, stream>>>(xb, wqkvT, b_qkv, nullptr, Qb, Kb, Vb,
                                                 MROWS, 3 * DMODEL, DMODEL);
    transp_bf16_head<<<dim3(2, 64, BATCH * NHEADS), dim3(32, 8), 0, stream>>>(Vb, Vt);
    attn_kernel<<<dim3(64, 8), 256, 0, stream>>>(Qb, Kb, Vt, Yatt);
    gemm256<1><<<dim3(4, 32), 512, 0, stream>>>(Yatt, wprojT, b_proj, out, nullptr, nullptr,
                                                nullptr, MROWS, DMODEL, DMODEL);
}

// Round 4
// 261.738 us; speedup vs baseline: 1.0554x; 1.0554x over previous
//
#include <hip/hip_runtime.h>
#include <stdint.h>

#define BATCH 4
#define SEQ 2048
#define DMODEL 1024
#define NHEADS 16
#define HDIM 64
#define MROWS (BATCH * SEQ)   // 8192

typedef float floatx4 __attribute__((ext_vector_type(4)));
typedef __bf16 bf16x8 __attribute__((ext_vector_type(8)));
typedef __bf16 bf16x4 __attribute__((ext_vector_type(4)));
typedef short short8 __attribute__((ext_vector_type(8)));

__device__ __forceinline__ unsigned short f32_to_bf16(float f) {
    union { float f; unsigned int u; } c; c.f = f;
    unsigned int u = c.u;
    unsigned int r = (u + 0x7FFFu + ((u >> 16) & 1u)) >> 16;
    return (unsigned short)r;
}

// async global->LDS 16B per lane (LDS dest = wave-uniform base + lane*16)
__device__ __forceinline__ void async_ld16(const void* g, void* l) {
    __builtin_amdgcn_global_load_lds(
        (const __attribute__((address_space(1))) unsigned int*)g,
        (__attribute__((address_space(3))) unsigned int*)l, 16, 0, 0);
}

#define BARRIER() do { asm volatile("" ::: "memory"); \
    __builtin_amdgcn_s_barrier(); asm volatile("" ::: "memory"); } while (0)

// ---------------------------------------------------------------- convert x
__global__ __launch_bounds__(256) void conv_f32_bf16(
    const float* __restrict__ in, unsigned short* __restrict__ out, int n4) {
    int i = blockIdx.x * 256 + threadIdx.x;
    if (i < n4) {
        float4 v = ((const float4*)in)[i];
        ushort4 o;
        o.x = f32_to_bf16(v.x); o.y = f32_to_bf16(v.y);
        o.z = f32_to_bf16(v.z); o.w = f32_to_bf16(v.w);
        ((ushort4*)out)[i] = o;
    }
}

// ------------------------------------------- transpose+convert W [K,N] -> [N,K] bf16
__global__ __launch_bounds__(256) void transp_conv(
    const float* __restrict__ in, unsigned short* __restrict__ out, int K, int N) {
    __shared__ float tile[32][33];
    int bx = blockIdx.x * 32;  // n
    int by = blockIdx.y * 32;  // k
    int tx = threadIdx.x, ty = threadIdx.y;
#pragma unroll
    for (int i = 0; i < 4; ++i)
        tile[ty + i * 8][tx] = in[(size_t)(by + ty + i * 8) * N + bx + tx];
    __syncthreads();
#pragma unroll
    for (int i = 0; i < 4; ++i)
        out[(size_t)(bx + ty + i * 8) * K + by + tx] = f32_to_bf16(tile[tx][ty + i * 8]);
}

// --------------- per-head bf16 transpose [T,64] -> [64,T], keys PERMUTED within
// each 64-tile: k2 = (k&15)*4 + (k>>4)&3  (must match attn's packed-P layout)
__global__ __launch_bounds__(256) void transp_bf16_head(
    const unsigned short* __restrict__ in, unsigned short* __restrict__ out) {
    __shared__ unsigned short tile[32][33];
    const unsigned short* src = in + (size_t)blockIdx.z * SEQ * HDIM;
    unsigned short* dst = out + (size_t)blockIdx.z * SEQ * HDIM;
    int bx = blockIdx.x * 32;  // d block
    int by = blockIdx.y * 32;  // t block
    int tx = threadIdx.x, ty = threadIdx.y;
#pragma unroll
    for (int i = 0; i < 4; ++i)
        tile[ty + i * 8][tx] = src[(size_t)(by + ty + i * 8) * HDIM + bx + tx];
    __syncthreads();
#pragma unroll
    for (int i = 0; i < 4; ++i) {
        int keyg = by + tx;
        int col2 = (keyg & ~63) | (((keyg & 15) << 2) | ((keyg >> 4) & 3));
        dst[(size_t)(bx + ty + i * 8) * SEQ + col2] = tile[tx][ty + i * 8];
    }
}

// ---------------------------------------------------------------- GEMM 256x256, 8-phase
// v2 (swizzle FIXED): 512 thr / 8 waves (2Mx4N), BK=64, LDS 128KB.
// Bank swizzle: 128B row = 8 x 16B slots; physical slot = logical slot ^ (row&7).
// Applied BOTH sides (rule #21): staging source slot = (tid&7)^((tid>>3)&7) with
// linear LDS dest; ds_read slot = (kk*4+quad)^(l16&7). 16 lanes/slot-group now
// spread over all 8 bank groups -> 2 lanes/bank = conflict-free (m136). Same
// pattern as attn staging below (measured 0 conflicts rounds 0-2).
// Stage unit = 64 rows x 128B = 1 gload_lds/thread; 8 units/tile; unit X(t+2)
// staged one phase after X(t)'s last ds_read:
//   ph1: B wn1,wn3 (t+1) | ph2: A rows0-63 (t+2) | ph3: B wn0,wn2 (t+2)
//   ph4: A rows64-127 (t+2)
// One vmcnt(6) per tile boundary (drains tile t's 8, leaves t+1's first 6 in
// flight); vmcnt(0) only entering the last tile.
template <int EPI>
__global__ __launch_bounds__(512, 1) void gemm256(
    const unsigned short* __restrict__ A, const unsigned short* __restrict__ Bt,
    const float* __restrict__ bias, float* __restrict__ Cout,
    unsigned short* __restrict__ Qo, unsigned short* __restrict__ Ko,
    unsigned short* __restrict__ Vo, int M, int N, int K) {
    __shared__ __align__(16) unsigned short ldsA[2][2][8192];  // [buf][half][128*64]
    __shared__ __align__(16) unsigned short ldsB[2][2][8192];

    const int tid = threadIdx.x;
    const int lane = tid & 63;
    const int w = tid >> 6;              // 0..7
    const int wm = w >> 2, wn = w & 3;   // 2 x 4
    const int quad = lane >> 4, l16 = lane & 15;
    const int m0 = blockIdx.y * 256;
    const int n0 = blockIdx.x * 256;
    const int ldb = K * 2;               // row stride bytes (A and Bt)
    const int NT = K >> 6;               // 64-wide K tiles

    // ---- staging map: dest row = tid>>3 (0..63), dest slot = tid&7;
    //      source slot = dest slot ^ (row&7)  (involution; coalesced per 8 lanes)
    const int t16 = tid * 16;
    const int srow = tid >> 3;
    const int sslot = (tid & 7) ^ (srow & 7);
    const char* pAs = (const char*)A + (size_t)(m0 + srow) * ldb + sslot * 16;
    const char* pBs = (const char*)Bt + (size_t)(n0 + srow) * ldb + sslot * 16;
    char* ldA0 = (char*)&ldsA[0][0][0] + t16;
    char* ldB0 = (char*)&ldsB[0][0][0] + t16;

    // unit uu: A: half*2+quarter (rows uu&1?64-127:0-63 of half uu>>1)
    //          B: 64-row slice of wave wn=uu. LDS byte = buf*32768 + uu*8192 + t16
    auto stA = [&](int kt, int uu) {
        async_ld16(pAs + (size_t)uu * 64 * ldb + kt * 128,
                   ldA0 + ((kt & 1) << 15) + (uu << 13));
    };
    auto stB = [&](int kt, int uu) {
        async_ld16(pBs + (size_t)uu * 64 * ldb + kt * 128,
                   ldB0 + ((kt & 1) << 15) + (uu << 13));
    };

    floatx4 acc[8][4];
#pragma unroll
    for (int mf = 0; mf < 8; ++mf)
#pragma unroll
        for (int nf = 0; nf < 4; ++nf) acc[mf][nf] = (floatx4){0.f, 0.f, 0.f, 0.f};

    // ---- prologue: tile0 all 8 units, then tile1's first 6 (issue order = drain order)
    stA(0, 0); stA(0, 1); stA(0, 2); stA(0, 3);
    stB(0, 0); stB(0, 1); stB(0, 2); stB(0, 3);
    if (NT > 1) {
        stA(1, 0); stA(1, 2);
        stB(1, 0); stB(1, 2);
        stA(1, 1); stA(1, 3);
    }

#define MFMA16(dst, af, bf) dst = __builtin_amdgcn_mfma_f32_16x16x32_bf16(af, bf, dst, 0, 0, 0)
    // swizzled fragment read: row, logical slot s (0..7) -> elements
#define RD(base, row, s) (*(const bf16x8*)&(base)[(row) * 64 + (((s) ^ ((row) & 7)) << 3)])

    for (int t = 0; t < NT; ++t) {
        const int b = t & 1;
        if (t + 1 < NT) asm volatile("s_waitcnt vmcnt(6)" ::: "memory");
        else            asm volatile("s_waitcnt vmcnt(0)" ::: "memory");
        BARRIER();  // tile t fully landed in every wave's LDS slice

        const unsigned short* Ab = &ldsA[b][wm][0];
        const unsigned short* Bb = &ldsB[b][wn >> 1][(wn & 1) * 4096];

        bf16x8 aR[4][2], bR[4][2];

        // ---- phase 1: read A Mf0-3 (8) + B Nf0-1 (4); stage B wn1,wn3 (t+1)
#pragma unroll
        for (int mf = 0; mf < 4; ++mf)
#pragma unroll
            for (int kk = 0; kk < 2; ++kk)
                aR[mf][kk] = RD(Ab, mf * 16 + l16, kk * 4 + quad);
#pragma unroll
        for (int nf = 0; nf < 2; ++nf)
#pragma unroll
            for (int kk = 0; kk < 2; ++kk)
                bR[nf][kk] = RD(Bb, nf * 16 + l16, kk * 4 + quad);
        if (t + 1 < NT) { stB(t + 1, 1); stB(t + 1, 3); }
        BARRIER();
        __builtin_amdgcn_s_setprio(1);
#pragma unroll
        for (int mf = 0; mf < 4; ++mf)
#pragma unroll
            for (int nf = 0; nf < 2; ++nf)
#pragma unroll
                for (int kk = 0; kk < 2; ++kk)
                    MFMA16(acc[mf][nf], aR[mf][kk], bR[nf][kk]);
        __builtin_amdgcn_s_setprio(0);
        BARRIER();

        // ---- phase 2: read B Nf2-3 (4); stage A rows0-63 (t+2); MFMA q(0, hi-N)
#pragma unroll
        for (int nf = 2; nf < 4; ++nf)
#pragma unroll
            for (int kk = 0; kk < 2; ++kk)
                bR[nf][kk] = RD(Bb, nf * 16 + l16, kk * 4 + quad);
        if (t + 2 < NT) { stA(t + 2, 0); stA(t + 2, 2); }
        BARRIER();
        __builtin_amdgcn_s_setprio(1);
#pragma unroll
        for (int mf = 0; mf < 4; ++mf)
#pragma unroll
            for (int nf = 2; nf < 4; ++nf)
#pragma unroll
                for (int kk = 0; kk < 2; ++kk)
                    MFMA16(acc[mf][nf], aR[mf][kk], bR[nf][kk]);
        __builtin_amdgcn_s_setprio(0);
        BARRIER();

        // ---- phase 3: read A Mf4-7 (8); stage B wn0,wn2 (t+2); MFMA q(1, hi-N)
#pragma unroll
        for (int mf = 0; mf < 4; ++mf)
#pragma unroll
            for (int kk = 0; kk < 2; ++kk)
                aR[mf][kk] = RD(Ab, (mf + 4) * 16 + l16, kk * 4 + quad);
        if (t + 2 < NT) { stB(t + 2, 0); stB(t + 2, 2); }
        BARRIER();
        __builtin_amdgcn_s_setprio(1);
#pragma unroll
        for (int mf = 0; mf < 4; ++mf)
#pragma unroll
            for (int nf = 2; nf < 4; ++nf)
#pragma unroll
                for (int kk = 0; kk < 2; ++kk)
                    MFMA16(acc[mf + 4][nf], aR[mf][kk], bR[nf][kk]);
        __builtin_amdgcn_s_setprio(0);
        BARRIER();

        // ---- phase 4: stage A rows64-127 (t+2); MFMA q(1, lo-N) (B lo kept live)
        if (t + 2 < NT) { stA(t + 2, 1); stA(t + 2, 3); }
        BARRIER();
        __builtin_amdgcn_s_setprio(1);
#pragma unroll
        for (int mf = 0; mf < 4; ++mf)
#pragma unroll
            for (int nf = 0; nf < 2; ++nf)
#pragma unroll
                for (int kk = 0; kk < 2; ++kk)
                    MFMA16(acc[mf + 4][nf], aR[mf][kk], bR[nf][kk]);
        __builtin_amdgcn_s_setprio(0);
        // tile boundary (wait + barrier) at loop top
    }
#undef RD
#undef MFMA16

    // ---- epilogue
#pragma unroll
    for (int mf = 0; mf < 8; ++mf)
#pragma unroll
        for (int nf = 0; nf < 4; ++nf)
#pragma unroll
            for (int r = 0; r < 4; ++r) {
                int m = m0 + wm * 128 + mf * 16 + quad * 4 + r;
                int n = n0 + wn * 64 + nf * 16 + l16;
                float v = acc[mf][nf][r] + bias[n];
                if (EPI == 1) {
                    Cout[(size_t)m * N + n] = v;
                } else {
                    int sel = n >> 10, c = n & 1023;
                    int head = c >> 6, d = c & 63;
                    int bb = m >> 11, tt = m & 2047;
                    unsigned short* dst = sel == 0 ? Qo : (sel == 1 ? Ko : Vo);
                    dst[((((size_t)bb * NHEADS + head) * SEQ + tt) << 6) + d] = f32_to_bf16(v);
                }
            }
}

// ---------------------------------------------------------------- GEMM 128x128 (proj)
// Round-2 structure: 3-buffer LDS, prefetch distance 2, counted vmcnt + raw barrier.
// Used for proj (N=1024): 512 balanced blocks vs gemm256's 128 (half the CUs idle).
template <int EPI>
__global__ __launch_bounds__(256, 3) void gemm_bt(
    const unsigned short* __restrict__ A, const unsigned short* __restrict__ Bt,
    const float* __restrict__ bias, float* __restrict__ Cout,
    unsigned short* __restrict__ Qo, unsigned short* __restrict__ Ko,
    unsigned short* __restrict__ Vo, int M, int N, int K) {
    __shared__ __align__(16) unsigned short As[3][128 * 32];
    __shared__ __align__(16) unsigned short Bs[3][128 * 32];
    const int tid = threadIdx.x;
    const int lane = tid & 63;
    const int w = tid >> 6;
    const int wm = w & 1, wn = w >> 1;
    const int quad = lane >> 4, l16 = lane & 15;
    const int m0 = blockIdx.y * 128;
    const int n0 = blockIdx.x * 128;
    const int fsw = (l16 >> 1) & 3;

    const int idx0 = tid, idx1 = tid + 256;
    const int row0 = idx0 >> 2, row1 = idx1 >> 2;
    const int cg0 = (idx0 & 3) ^ ((row0 >> 1) & 3);
    const int cg1 = (idx1 & 3) ^ ((row1 >> 1) & 3);
    const unsigned short* Ar0 = &A[(size_t)(m0 + row0) * K + cg0 * 8];
    const unsigned short* Ar1 = &A[(size_t)(m0 + row1) * K + cg1 * 8];
    const unsigned short* Br0 = &Bt[(size_t)(n0 + row0) * K + cg0 * 8];
    const unsigned short* Br1 = &Bt[(size_t)(n0 + row1) * K + cg1 * 8];

    floatx4 acc[4][4];
#pragma unroll
    for (int mt = 0; mt < 4; ++mt)
#pragma unroll
        for (int nt = 0; nt < 4; ++nt) acc[mt][nt] = (floatx4){0.f, 0.f, 0.f, 0.f};

    async_ld16(Ar0, &As[0][idx0 * 8]);
    async_ld16(Br0, &Bs[0][idx0 * 8]);
    async_ld16(Ar1, &As[0][idx1 * 8]);
    async_ld16(Br1, &Bs[0][idx1 * 8]);
    async_ld16(Ar0 + 32, &As[1][idx0 * 8]);
    async_ld16(Br0 + 32, &Bs[1][idx0 * 8]);
    async_ld16(Ar1 + 32, &As[1][idx1 * 8]);
    async_ld16(Br1 + 32, &Bs[1][idx1 * 8]);

    const int nk = K >> 5;
    int bcur = 0, bpre = 2;
    for (int kt = 0; kt < nk; ++kt) {
        if (kt + 2 < nk)
            asm volatile("s_waitcnt vmcnt(4)" ::: "memory");
        else
            asm volatile("s_waitcnt vmcnt(0)" ::: "memory");
        __builtin_amdgcn_s_barrier();
        asm volatile("" ::: "memory");

        if (kt + 2 < nk) {
            const int ko = (kt + 2) << 5;
            async_ld16(Ar0 + ko, &As[bpre][idx0 * 8]);
            async_ld16(Br0 + ko, &Bs[bpre][idx0 * 8]);
            async_ld16(Ar1 + ko, &As[bpre][idx1 * 8]);
            async_ld16(Br1 + ko, &Bs[bpre][idx1 * 8]);
        }

        bf16x8 aF[4], bF[4];
#pragma unroll
        for (int mt = 0; mt < 4; ++mt)
            aF[mt] = *(const bf16x8*)&As[bcur][(wm * 64 + mt * 16 + l16) * 32 + (quad ^ fsw) * 8];
#pragma unroll
        for (int nt = 0; nt < 4; ++nt)
            bF[nt] = *(const bf16x8*)&Bs[bcur][(wn * 64 + nt * 16 + l16) * 32 + (quad ^ fsw) * 8];
#pragma unroll
        for (int mt = 0; mt < 4; ++mt)
#pragma unroll
            for (int nt = 0; nt < 4; ++nt)
                acc[mt][nt] = __builtin_amdgcn_mfma_f32_16x16x32_bf16(
                    aF[mt], bF[nt], acc[mt][nt], 0, 0, 0);

        bcur = (bcur == 2) ? 0 : bcur + 1;
        bpre = (bpre == 2) ? 0 : bpre + 1;
    }

#pragma unroll
    for (int mt = 0; mt < 4; ++mt)
#pragma unroll
        for (int nt = 0; nt < 4; ++nt)
#pragma unroll
            for (int r = 0; r < 4; ++r) {
                int m = m0 + wm * 64 + mt * 16 + quad * 4 + r;
                int n = n0 + wn * 64 + nt * 16 + l16;
                float v = acc[mt][nt][r] + bias[n];
                if (EPI == 1) {
                    Cout[(size_t)m * N + n] = v;
                } else {
                    int sel = n >> 10, c = n & 1023;
                    int head = c >> 6, d = c & 63;
                    int bb = m >> 11, t = m & 2047;
                    unsigned short* dst = sel == 0 ? Qo : (sel == 1 ? Ko : Vo);
                    dst[((((size_t)bb * NHEADS + head) * SEQ + t) << 6) + d] = f32_to_bf16(v);
                }
            }
}

// ---------------------------------------------------------------- flash attention v9
// Block-shared double-buffered K/V LDS staging via global_load_lds (coalesced 1KB
// DMA per instr, source chunk-swizzled, dest lane-linear). 4 waves/block share one
// bh; strips (sA, 63-sA); block-uniform tile counts (2by+2, 32-2by) = 34 total, so
// barriers never diverge (short waves' extra tiles fully masked -> P=0, harmless).
// Prefetch issued AFTER the barrier so the barrier drain hits landed loads.
// Numerics identical to R8: no-max exp2, packed-P per-wave LDS, MFMA-ones lsum.
__global__ __launch_bounds__(256, 2) void attn_kernel(
    const unsigned short* __restrict__ Qg, const unsigned short* __restrict__ Kg,
    const unsigned short* __restrict__ Vtg, unsigned short* __restrict__ Yatt) {
    __shared__ __align__(16) unsigned short Kb2[2][4096];  // [buf][key][d]   8KB each
    __shared__ __align__(16) unsigned short Vb2[2][4096];  // [buf][d][key~]  8KB each
    __shared__ __align__(16) unsigned short Ps[4][2048];   // per-wave packed P

    const int tid = threadIdx.x;
    const int lane = tid & 63;
    const int w = tid >> 6;
    const int quad = lane >> 4, l16 = lane & 15;
    const int bh = blockIdx.x;           // 0..63 -> XCD bh%8 (L2 locality)
    const int by = blockIdx.y;           // 0..7
    const int sA = by * 4 + w;           // strip 0..31 (mirror = 63-sA)
    const size_t base = (size_t)bh * SEQ * HDIM;
    const int bIdx = bh >> 4, h = bh & 15;
    unsigned short* Pw = &Ps[w][0];
    const float csc = 0.18033688f;  // 0.125 * log2(e)

    const int lrow = lane >> 3;                 // 0..7 within a DMA instr
    const int lch = (lane & 7) ^ lrow;          // source chunk (store-swizzle ^ row&7)

    short8 osv = {0x3F80, 0x3F80, 0x3F80, 0x3F80, 0x3F80, 0x3F80, 0x3F80, 0x3F80};
    bf16x8 ones = __builtin_bit_cast(bf16x8, osv);

    for (int half = 0; half < 2; ++half) {
        const int rowb = (half == 0 ? sA : 63 - sA) * 32;
        const int kmaxB = (half == 0) ? (2 * by + 2) : (32 - 2 * by);  // block-uniform

        // Q fragments -> registers
        bf16x8 qf[2][2];
#pragma unroll
        for (int mt = 0; mt < 2; ++mt)
#pragma unroll
            for (int kk = 0; kk < 2; ++kk)
                qf[mt][kk] = *(const bf16x8*)&Qg[base + (size_t)(rowb + mt * 16 + l16) * 64 +
                                                 kk * 32 + quad * 8];

        floatx4 lsum[2];
        floatx4 o[2][4];
#pragma unroll
        for (int mt = 0; mt < 2; ++mt) {
            lsum[mt] = (floatx4){0.f, 0.f, 0.f, 0.f};
#pragma unroll
            for (int nt = 0; nt < 4; ++nt) o[mt][nt] = (floatx4){0.f, 0.f, 0.f, 0.f};
        }

        // prologue: stage tile 0 into buf 0 (wave's 2+2 DMA instructions)
        // (safe w/o extra barrier: half-0 kmaxB is even, so buf0's last half-0 use
        //  finished before the final half-0 barrier)
        {
            const unsigned short* Ktg = Kg + base;
            const unsigned short* Vtg_t = Vtg + base;
#pragma unroll
            for (int ii = 0; ii < 2; ++ii) {
                int i = w * 2 + ii;
                async_ld16(Ktg + (i * 8 + lrow) * 64 + lch * 8,
                           &Kb2[0][i * 512 + lane * 8]);
                async_ld16(Vtg_t + (size_t)(i * 8 + lrow) * SEQ + lch * 8,
                           &Vb2[0][i * 512 + lane * 8]);
            }
        }

        for (int kb = 0; kb < kmaxB; ++kb) {
            const int b = kb & 1;
            __syncthreads();  // drains own DMA (tile kb landed); syncs buffer reuse

            if (kb + 1 < kmaxB) {  // prefetch AFTER barrier -> survives the drain
                const unsigned short* Ktg = Kg + base + (size_t)(kb + 1) * 64 * HDIM;
                const unsigned short* Vtg_t = Vtg + base + (kb + 1) * 64;
#pragma unroll
                for (int ii = 0; ii < 2; ++ii) {
                    int i = w * 2 + ii;
                    async_ld16(Ktg + (i * 8 + lrow) * 64 + lch * 8,
                               &Kb2[1 - b][i * 512 + lane * 8]);
                    async_ld16(Vtg_t + (size_t)(i * 8 + lrow) * SEQ + lch * 8,
                               &Vb2[1 - b][i * 512 + lane * 8]);
                }
            }

            // S = Q K^T : fragments from LDS (swizzle chunk ^ (l16&7))
            floatx4 s[2][4];
#pragma unroll
            for (int mt = 0; mt < 2; ++mt)
#pragma unroll
                for (int nt = 0; nt < 4; ++nt) s[mt][nt] = (floatx4){0.f, 0.f, 0.f, 0.f};
#pragma unroll
            for (int kk = 0; kk < 2; ++kk) {
                bf16x8 kf[4];
#pragma unroll
                for (int nt = 0; nt < 4; ++nt)
                    kf[nt] = *(const bf16x8*)&Kb2[b][(nt * 16 + l16) * 64 +
                                                     ((kk * 4 + quad) ^ (l16 & 7)) * 8];
#pragma unroll
                for (int nt = 0; nt < 4; ++nt)
#pragma unroll
                    for (int mt = 0; mt < 2; ++mt)
                        s[mt][nt] = __builtin_amdgcn_mfma_f32_16x16x32_bf16(
                            qf[mt][kk], kf[nt], s[mt][nt], 0, 0, 0);
            }

            if ((kb * 64 + 63) > rowb) {  // wave-uniform; also covers extra tiles
#pragma unroll
                for (int mt = 0; mt < 2; ++mt)
#pragma unroll
                    for (int nt = 0; nt < 4; ++nt)
#pragma unroll
                        for (int r = 0; r < 4; ++r) {
                            int key = kb * 64 + nt * 16 + l16;
                            int qrow = rowb + mt * 16 + quad * 4 + r;
                            if (key > qrow) s[mt][nt][r] = -INFINITY;
                        }
            }

            // p = exp2(score * 0.125*log2e) == exp(score/8); no max subtraction
#pragma unroll
            for (int mt = 0; mt < 2; ++mt)
#pragma unroll
                for (int nt = 0; nt < 4; ++nt)
#pragma unroll
                    for (int r = 0; r < 4; ++r)
                        s[mt][nt][r] = __builtin_amdgcn_exp2f(s[mt][nt][r] * csc);

            // P -> per-wave LDS, packed slots k2 = l16*4+nt; swizzled by (prow&14)
#pragma unroll
            for (int mt = 0; mt < 2; ++mt)
#pragma unroll
                for (int r = 0; r < 4; ++r) {
                    int prow = mt * 16 + quad * 4 + r;
                    int unit = l16 ^ (prow & 14);
                    floatx4 t = {s[mt][0][r], s[mt][1][r], s[mt][2][r], s[mt][3][r]};
                    bf16x4 pv = __builtin_convertvector(t, bf16x4);
                    *(bf16x4*)&Pw[prow * 64 + unit * 4] = pv;
                }

            // O += P V ; l += P 1   (V^T pre-permuted to packed key order)
#pragma unroll
            for (int kk = 0; kk < 2; ++kk) {
                bf16x8 af[2];
#pragma unroll
                for (int mt = 0; mt < 2; ++mt) {
                    int prow = mt * 16 + l16;
                    int u2 = (kk * 8 + quad * 2) ^ (l16 & 14);
                    af[mt] = *(const bf16x8*)&Pw[prow * 64 + u2 * 4];
                }
#pragma unroll
                for (int nt = 0; nt < 4; ++nt) {
                    bf16x8 vf = *(const bf16x8*)&Vb2[b][(nt * 16 + l16) * 64 +
                                                        ((kk * 4 + quad) ^ (l16 & 7)) * 8];
#pragma unroll
                    for (int mt = 0; mt < 2; ++mt)
                        o[mt][nt] = __builtin_amdgcn_mfma_f32_16x16x32_bf16(
                            af[mt], vf, o[mt][nt], 0, 0, 0);
                }
#pragma unroll
                for (int mt = 0; mt < 2; ++mt)
                    lsum[mt] = __builtin_amdgcn_mfma_f32_16x16x32_bf16(
                        af[mt], ones, lsum[mt], 0, 0, 0);
            }
        }

#pragma unroll
        for (int mt = 0; mt < 2; ++mt)
#pragma unroll
            for (int r = 0; r < 4; ++r) {
                float inv = 1.0f / lsum[mt][r];
                int qrow = rowb + mt * 16 + quad * 4 + r;
#pragma unroll
                for (int nt = 0; nt < 4; ++nt)
                    Yatt[((size_t)(bIdx * SEQ + qrow) << 10) + h * 64 + nt * 16 + l16] =
                        f32_to_bf16(o[mt][nt][r] * inv);
            }
    }
}

// ---------------------------------------------------------------- launch
extern "C" void kernel_launch(void* const* d_in, const int* in_sizes, int n_in,
                              void* d_out, int out_size, void* d_ws, size_t ws_size,
                              hipStream_t stream) {
    const float* x = (const float*)d_in[0];
    const float* w_qkv = (const float*)d_in[1];
    const float* b_qkv = (const float*)d_in[2];
    const float* w_proj = (const float*)d_in[3];
    const float* b_proj = (const float*)d_in[4];
    float* out = (float*)d_out;

    char* ws = (char*)d_ws;
    unsigned short* xb     = (unsigned short*)(ws);                       // 16 MB
    unsigned short* wqkvT  = (unsigned short*)(ws + 16777216);            // 6 MB
    unsigned short* wprojT = (unsigned short*)(ws + 23068672);            // 2 MB
    unsigned short* Qb     = (unsigned short*)(ws + 25165824);            // 16 MB
    unsigned short* Kb     = (unsigned short*)(ws + 41943040);            // 16 MB
    unsigned short* Vb     = (unsigned short*)(ws + 58720256);            // 16 MB
    unsigned short* Yatt   = (unsigned short*)(ws + 75497472);            // 16 MB
    unsigned short* Vt     = (unsigned short*)(ws + 92274688);            // 16 MB

    conv_f32_bf16<<<8192, 256, 0, stream>>>(x, xb, (MROWS * DMODEL) / 4);
    transp_conv<<<dim3(96, 32), dim3(32, 8), 0, stream>>>(w_qkv, wqkvT, DMODEL, 3 * DMODEL);
    transp_conv<<<dim3(32, 32), dim3(32, 8), 0, stream>>>(w_proj, wprojT, DMODEL, DMODEL);
    gemm256<0><<<dim3(12, 32), 512, 0, stream>>>(xb, wqkvT, b_qkv, nullptr, Qb, Kb, Vb,
                                                 MROWS, 3 * DMODEL, DMODEL);
    transp_bf16_head<<<dim3(2, 64, BATCH * NHEADS), dim3(32, 8), 0, stream>>>(Vb, Vt);
    attn_kernel<<<dim3(64, 8), 256, 0, stream>>>(Qb, Kb, Vt, Yatt);
    gemm_bt<1><<<dim3(8, 64), 256, 0, stream>>>(Yatt, wprojT, b_proj, out, nullptr, nullptr,
                                                nullptr, MROWS, DMODEL, DMODEL);
}

// Round 5
// 253.324 us; speedup vs baseline: 1.0905x; 1.0332x over previous
//
#include <hip/hip_runtime.h>
#include <stdint.h>

#define BATCH 4
#define SEQ 2048
#define DMODEL 1024
#define NHEADS 16
#define HDIM 64
#define MROWS (BATCH * SEQ)   // 8192

typedef float floatx4 __attribute__((ext_vector_type(4)));
typedef __bf16 bf16x8 __attribute__((ext_vector_type(8)));
typedef __bf16 bf16x4 __attribute__((ext_vector_type(4)));
typedef short short8 __attribute__((ext_vector_type(8)));

__device__ __forceinline__ unsigned short f32_to_bf16(float f) {
    union { float f; unsigned int u; } c; c.f = f;
    unsigned int u = c.u;
    unsigned int r = (u + 0x7FFFu + ((u >> 16) & 1u)) >> 16;
    return (unsigned short)r;
}

// async global->LDS 16B per lane (m97 pattern; LDS dest must equal base + lane*16)
__device__ __forceinline__ void async_ld16(const void* g, void* l) {
    __builtin_amdgcn_global_load_lds(
        (const __attribute__((address_space(1))) unsigned int*)g,
        (__attribute__((address_space(3))) unsigned int*)l, 16, 0, 0);
}

// ---------------------------------------------------------------- convert x
__global__ __launch_bounds__(256) void conv_f32_bf16(
    const float* __restrict__ in, unsigned short* __restrict__ out, int n4) {
    int i = blockIdx.x * 256 + threadIdx.x;
    if (i < n4) {
        float4 v = ((const float4*)in)[i];
        ushort4 o;
        o.x = f32_to_bf16(v.x); o.y = f32_to_bf16(v.y);
        o.z = f32_to_bf16(v.z); o.w = f32_to_bf16(v.w);
        ((ushort4*)out)[i] = o;
    }
}

// ------------------------------------------- transpose+convert W [K,N] -> [N,K] bf16
__global__ __launch_bounds__(256) void transp_conv(
    const float* __restrict__ in, unsigned short* __restrict__ out, int K, int N) {
    __shared__ float tile[32][33];
    int bx = blockIdx.x * 32;  // n
    int by = blockIdx.y * 32;  // k
    int tx = threadIdx.x, ty = threadIdx.y;
#pragma unroll
    for (int i = 0; i < 4; ++i)
        tile[ty + i * 8][tx] = in[(size_t)(by + ty + i * 8) * N + bx + tx];
    __syncthreads();
#pragma unroll
    for (int i = 0; i < 4; ++i)
        out[(size_t)(bx + ty + i * 8) * K + by + tx] = f32_to_bf16(tile[tx][ty + i * 8]);
}

// --------------- per-head bf16 transpose [T,64] -> [64,T], keys PERMUTED within
// each 64-tile: k2 = (k&15)*4 + (k>>4)&3  (must match attn's packed-P layout)
__global__ __launch_bounds__(256) void transp_bf16_head(
    const unsigned short* __restrict__ in, unsigned short* __restrict__ out) {
    __shared__ unsigned short tile[32][33];
    const unsigned short* src = in + (size_t)blockIdx.z * SEQ * HDIM;
    unsigned short* dst = out + (size_t)blockIdx.z * SEQ * HDIM;
    int bx = blockIdx.x * 32;  // d block
    int by = blockIdx.y * 32;  // t block
    int tx = threadIdx.x, ty = threadIdx.y;
#pragma unroll
    for (int i = 0; i < 4; ++i)
        tile[ty + i * 8][tx] = src[(size_t)(by + ty + i * 8) * HDIM + bx + tx];
    __syncthreads();
#pragma unroll
    for (int i = 0; i < 4; ++i) {
        int keyg = by + tx;
        int col2 = (keyg & ~63) | (((keyg & 15) << 2) | ((keyg >> 4) & 3));
        dst[(size_t)(bx + ty + i * 8) * SEQ + col2] = tile[tx][ty + i * 8];
    }
}

// ---------------------------------------------------------------- GEMM (B^T input)
// Round-2 structure (proven 73us QKV): 3-buffer LDS, prefetch distance 2, counted
// vmcnt + raw barrier. NEW: XCD-aware block swizzle (T1) — dispatch round-robins
// XCDs, so swz=(lin&7)*q + lin>>3 gives each XCD a contiguous chunk of tiles
// (8 consecutive m-rows) -> A-panel slice + B panel fit (proj) or mostly fit (QKV)
// in the 4MB per-XCD L2. GEMM is latency-bound; converting ~900cyc HBM misses to
// ~200cyc L2 hits attacks the exposed-latency term directly. nwg%8==0 for both
// grids (1536, 512) -> bijective.
template <int EPI>
__global__ __launch_bounds__(256, 3) void gemm_bt(
    const unsigned short* __restrict__ A, const unsigned short* __restrict__ Bt,
    const float* __restrict__ bias, float* __restrict__ Cout,
    unsigned short* __restrict__ Qo, unsigned short* __restrict__ Ko,
    unsigned short* __restrict__ Vo, int M, int N, int K) {
    __shared__ __align__(16) unsigned short As[3][128 * 32];
    __shared__ __align__(16) unsigned short Bs[3][128 * 32];
    const int tid = threadIdx.x;
    const int lane = tid & 63;
    const int w = tid >> 6;
    const int wm = w & 1, wn = w >> 1;
    const int quad = lane >> 4, l16 = lane & 15;

    // XCD-aware swizzle (contiguous chunk per XCD; bijective since nwg%8==0)
    const int nbx = gridDim.x;
    const int nwg = nbx * gridDim.y;
    const int lin = blockIdx.y * nbx + blockIdx.x;
    const int swz = (lin & 7) * (nwg >> 3) + (lin >> 3);
    const int m0 = (swz / nbx) * 128;
    const int n0 = (swz % nbx) * 128;
    const int fsw = (l16 >> 1) & 3;

    const int idx0 = tid, idx1 = tid + 256;
    const int row0 = idx0 >> 2, row1 = idx1 >> 2;
    const int cg0 = (idx0 & 3) ^ ((row0 >> 1) & 3);
    const int cg1 = (idx1 & 3) ^ ((row1 >> 1) & 3);
    const unsigned short* Ar0 = &A[(size_t)(m0 + row0) * K + cg0 * 8];
    const unsigned short* Ar1 = &A[(size_t)(m0 + row1) * K + cg1 * 8];
    const unsigned short* Br0 = &Bt[(size_t)(n0 + row0) * K + cg0 * 8];
    const unsigned short* Br1 = &Bt[(size_t)(n0 + row1) * K + cg1 * 8];

    floatx4 acc[4][4];
#pragma unroll
    for (int mt = 0; mt < 4; ++mt)
#pragma unroll
        for (int nt = 0; nt < 4; ++nt) acc[mt][nt] = (floatx4){0.f, 0.f, 0.f, 0.f};

    // prologue: tile 0 -> buf 0, tile 1 -> buf 1 (program order = vmcnt drain order)
    async_ld16(Ar0, &As[0][idx0 * 8]);
    async_ld16(Br0, &Bs[0][idx0 * 8]);
    async_ld16(Ar1, &As[0][idx1 * 8]);
    async_ld16(Br1, &Bs[0][idx1 * 8]);
    async_ld16(Ar0 + 32, &As[1][idx0 * 8]);
    async_ld16(Br0 + 32, &Bs[1][idx0 * 8]);
    async_ld16(Ar1 + 32, &As[1][idx1 * 8]);
    async_ld16(Br1 + 32, &Bs[1][idx1 * 8]);

    const int nk = K >> 5;
    int bcur = 0, bpre = 2;
    for (int kt = 0; kt < nk; ++kt) {
        if (kt + 2 < nk)
            asm volatile("s_waitcnt vmcnt(4)" ::: "memory");
        else
            asm volatile("s_waitcnt vmcnt(0)" ::: "memory");
        __builtin_amdgcn_s_barrier();
        asm volatile("" ::: "memory");  // pin prefetch + ds_reads below the barrier

        if (kt + 2 < nk) {  // prefetch distance 2, issued AFTER the barrier
            const int ko = (kt + 2) << 5;
            async_ld16(Ar0 + ko, &As[bpre][idx0 * 8]);
            async_ld16(Br0 + ko, &Bs[bpre][idx0 * 8]);
            async_ld16(Ar1 + ko, &As[bpre][idx1 * 8]);
            async_ld16(Br1 + ko, &Bs[bpre][idx1 * 8]);
        }

        bf16x8 aF[4], bF[4];
#pragma unroll
        for (int mt = 0; mt < 4; ++mt)
            aF[mt] = *(const bf16x8*)&As[bcur][(wm * 64 + mt * 16 + l16) * 32 + (quad ^ fsw) * 8];
#pragma unroll
        for (int nt = 0; nt < 4; ++nt)
            bF[nt] = *(const bf16x8*)&Bs[bcur][(wn * 64 + nt * 16 + l16) * 32 + (quad ^ fsw) * 8];
#pragma unroll
        for (int mt = 0; mt < 4; ++mt)
#pragma unroll
            for (int nt = 0; nt < 4; ++nt)
                acc[mt][nt] = __builtin_amdgcn_mfma_f32_16x16x32_bf16(
                    aF[mt], bF[nt], acc[mt][nt], 0, 0, 0);

        bcur = (bcur == 2) ? 0 : bcur + 1;
        bpre = (bpre == 2) ? 0 : bpre + 1;
    }

#pragma unroll
    for (int mt = 0; mt < 4; ++mt)
#pragma unroll
        for (int nt = 0; nt < 4; ++nt)
#pragma unroll
            for (int r = 0; r < 4; ++r) {
                int m = m0 + wm * 64 + mt * 16 + quad * 4 + r;
                int n = n0 + wn * 64 + nt * 16 + l16;
                float v = acc[mt][nt][r] + bias[n];
                if (EPI == 1) {
                    Cout[(size_t)m * N + n] = v;
                } else {
                    int sel = n >> 10, c = n & 1023;
                    int head = c >> 6, d = c & 63;
                    int bb = m >> 11, t = m & 2047;
                    unsigned short* dst = sel == 0 ? Qo : (sel == 1 ? Ko : Vo);
                    dst[((((size_t)bb * NHEADS + head) * SEQ + t) << 6) + d] = f32_to_bf16(v);
                }
            }
}

// ---------------------------------------------------------------- flash attention v10
// v10: K/V staging upgraded to the round-2 GEMM pipeline — 3 buffers, prefetch
// distance 2, counted vmcnt(4) + raw barrier (never vmcnt(0) in steady state).
// Per-wave DMA count: 4/tile (2 K + 2 V). At kb=0 outstanding = Q(4)+t0(4)+t1(4);
// vmcnt(4) leaves exactly tile1's 4 in flight, drains Q+t0. Steady state: drains
// tile kb only. WAR: prefetch kb+2 -> buf (kb+2)%3, whose last reads were iter
// kb-1 (complete before this barrier). NEW: end-of-half __syncthreads() — with 3
// buffers the old "kmaxB even => buf0 free" invariant is gone, so the next half's
// prologue must wait for all waves' last-tile reads.
// Numerics unchanged: no-max exp2, packed-P per-wave LDS, MFMA-ones lsum.
__global__ __launch_bounds__(256, 2) void attn_kernel(
    const unsigned short* __restrict__ Qg, const unsigned short* __restrict__ Kg,
    const unsigned short* __restrict__ Vtg, unsigned short* __restrict__ Yatt) {
    __shared__ __align__(16) unsigned short Kb2[3][4096];  // [buf][key][d]   8KB each
    __shared__ __align__(16) unsigned short Vb2[3][4096];  // [buf][d][key~]  8KB each
    __shared__ __align__(16) unsigned short Ps[4][2048];   // per-wave packed P

    const int tid = threadIdx.x;
    const int lane = tid & 63;
    const int w = tid >> 6;
    const int quad = lane >> 4, l16 = lane & 15;
    const int bh = blockIdx.x;           // 0..63 -> XCD bh%8 (L2 locality)
    const int by = blockIdx.y;           // 0..7
    const int sA = by * 4 + w;           // strip 0..31 (mirror = 63-sA)
    const size_t base = (size_t)bh * SEQ * HDIM;
    const int bIdx = bh >> 4, h = bh & 15;
    unsigned short* Pw = &Ps[w][0];
    const float csc = 0.18033688f;  // 0.125 * log2(e)

    const int lrow = lane >> 3;                 // 0..7 within a DMA instr
    const int lch = (lane & 7) ^ lrow;          // source chunk (store-swizzle ^ row&7)

    short8 osv = {0x3F80, 0x3F80, 0x3F80, 0x3F80, 0x3F80, 0x3F80, 0x3F80, 0x3F80};
    bf16x8 ones = __builtin_bit_cast(bf16x8, osv);

    const unsigned short* Ktg = Kg + base;
    const unsigned short* Vtg_t = Vtg + base;
    const int i0 = w * 2, i1 = w * 2 + 1;
    const int kof0 = (i0 * 8 + lrow) * 64 + lch * 8;
    const int kof1 = (i1 * 8 + lrow) * 64 + lch * 8;
    const size_t vof0 = (size_t)(i0 * 8 + lrow) * SEQ + lch * 8;
    const size_t vof1 = (size_t)(i1 * 8 + lrow) * SEQ + lch * 8;
    const int ld0 = i0 * 512 + lane * 8;
    const int ld1 = i1 * 512 + lane * 8;

    for (int half = 0; half < 2; ++half) {
        const int rowb = (half == 0 ? sA : 63 - sA) * 32;
        const int kmaxB = (half == 0) ? (2 * by + 2) : (32 - 2 * by);  // block-uniform, >=2

        // Q fragments -> registers
        bf16x8 qf[2][2];
#pragma unroll
        for (int mt = 0; mt < 2; ++mt)
#pragma unroll
            for (int kk = 0; kk < 2; ++kk)
                qf[mt][kk] = *(const bf16x8*)&Qg[base + (size_t)(rowb + mt * 16 + l16) * 64 +
                                                 kk * 32 + quad * 8];

        floatx4 lsum[2];
        floatx4 o[2][4];
#pragma unroll
        for (int mt = 0; mt < 2; ++mt) {
            lsum[mt] = (floatx4){0.f, 0.f, 0.f, 0.f};
#pragma unroll
            for (int nt = 0; nt < 4; ++nt) o[mt][nt] = (floatx4){0.f, 0.f, 0.f, 0.f};
        }

        // prologue: tile 0 -> buf 0, tile 1 -> buf 1 (kmaxB >= 2 always)
        async_ld16(Ktg + kof0, &Kb2[0][ld0]);
        async_ld16(Vtg_t + vof0, &Vb2[0][ld0]);
        async_ld16(Ktg + kof1, &Kb2[0][ld1]);
        async_ld16(Vtg_t + vof1, &Vb2[0][ld1]);
        async_ld16(Ktg + 64 * HDIM + kof0, &Kb2[1][ld0]);
        async_ld16(Vtg_t + 64 + vof0, &Vb2[1][ld0]);
        async_ld16(Ktg + 64 * HDIM + kof1, &Kb2[1][ld1]);
        async_ld16(Vtg_t + 64 + vof1, &Vb2[1][ld1]);

        int bcur = 0, bpre = 2;
        for (int kb = 0; kb < kmaxB; ++kb) {
            if (kb + 2 < kmaxB)
                asm volatile("s_waitcnt vmcnt(4)" ::: "memory");
            else
                asm volatile("s_waitcnt vmcnt(0)" ::: "memory");
            __builtin_amdgcn_s_barrier();
            asm volatile("" ::: "memory");

            if (kb + 2 < kmaxB) {  // prefetch distance 2, AFTER the barrier
                const unsigned short* Kt2 = Ktg + (size_t)(kb + 2) * 64 * HDIM;
                const unsigned short* Vt2 = Vtg_t + (kb + 2) * 64;
                async_ld16(Kt2 + kof0, &Kb2[bpre][ld0]);
                async_ld16(Vt2 + vof0, &Vb2[bpre][ld0]);
                async_ld16(Kt2 + kof1, &Kb2[bpre][ld1]);
                async_ld16(Vt2 + vof1, &Vb2[bpre][ld1]);
            }

            // S = Q K^T : fragments from LDS (swizzle chunk ^ (l16&7))
            floatx4 s[2][4];
#pragma unroll
            for (int mt = 0; mt < 2; ++mt)
#pragma unroll
                for (int nt = 0; nt < 4; ++nt) s[mt][nt] = (floatx4){0.f, 0.f, 0.f, 0.f};
#pragma unroll
            for (int kk = 0; kk < 2; ++kk) {
                bf16x8 kf[4];
#pragma unroll
                for (int nt = 0; nt < 4; ++nt)
                    kf[nt] = *(const bf16x8*)&Kb2[bcur][(nt * 16 + l16) * 64 +
                                                        ((kk * 4 + quad) ^ (l16 & 7)) * 8];
#pragma unroll
                for (int nt = 0; nt < 4; ++nt)
#pragma unroll
                    for (int mt = 0; mt < 2; ++mt)
                        s[mt][nt] = __builtin_amdgcn_mfma_f32_16x16x32_bf16(
                            qf[mt][kk], kf[nt], s[mt][nt], 0, 0, 0);
            }

            if ((kb * 64 + 63) > rowb) {  // wave-uniform; also covers extra tiles
#pragma unroll
                for (int mt = 0; mt < 2; ++mt)
#pragma unroll
                    for (int nt = 0; nt < 4; ++nt)
#pragma unroll
                        for (int r = 0; r < 4; ++r) {
                            int key = kb * 64 + nt * 16 + l16;
                            int qrow = rowb + mt * 16 + quad * 4 + r;
                            if (key > qrow) s[mt][nt][r] = -INFINITY;
                        }
            }

            // p = exp2(score * 0.125*log2e) == exp(score/8); no max subtraction
#pragma unroll
            for (int mt = 0; mt < 2; ++mt)
#pragma unroll
                for (int nt = 0; nt < 4; ++nt)
#pragma unroll
                    for (int r = 0; r < 4; ++r)
                        s[mt][nt][r] = __builtin_amdgcn_exp2f(s[mt][nt][r] * csc);

            // P -> per-wave LDS, packed slots k2 = l16*4+nt; swizzled by (prow&14)
#pragma unroll
            for (int mt = 0; mt < 2; ++mt)
#pragma unroll
                for (int r = 0; r < 4; ++r) {
                    int prow = mt * 16 + quad * 4 + r;
                    int unit = l16 ^ (prow & 14);
                    floatx4 t = {s[mt][0][r], s[mt][1][r], s[mt][2][r], s[mt][3][r]};
                    bf16x4 pv = __builtin_convertvector(t, bf16x4);
                    *(bf16x4*)&Pw[prow * 64 + unit * 4] = pv;
                }

            // O += P V ; l += P 1   (V^T pre-permuted to packed key order)
#pragma unroll
            for (int kk = 0; kk < 2; ++kk) {
                bf16x8 af[2];
#pragma unroll
                for (int mt = 0; mt < 2; ++mt) {
                    int prow = mt * 16 + l16;
                    int u2 = (kk * 8 + quad * 2) ^ (l16 & 14);
                    af[mt] = *(const bf16x8*)&Pw[prow * 64 + u2 * 4];
                }
#pragma unroll
                for (int nt = 0; nt < 4; ++nt) {
                    bf16x8 vf = *(const bf16x8*)&Vb2[bcur][(nt * 16 + l16) * 64 +
                                                           ((kk * 4 + quad) ^ (l16 & 7)) * 8];
#pragma unroll
                    for (int mt = 0; mt < 2; ++mt)
                        o[mt][nt] = __builtin_amdgcn_mfma_f32_16x16x32_bf16(
                            af[mt], vf, o[mt][nt], 0, 0, 0);
                }
#pragma unroll
                for (int mt = 0; mt < 2; ++mt)
                    lsum[mt] = __builtin_amdgcn_mfma_f32_16x16x32_bf16(
                        af[mt], ones, lsum[mt], 0, 0, 0);
            }

            bcur = (bcur == 2) ? 0 : bcur + 1;
            bpre = (bpre == 2) ? 0 : bpre + 1;
        }

        // all waves done reading K/V buffers before next half's prologue overwrites
        __syncthreads();

#pragma unroll
        for (int mt = 0; mt < 2; ++mt)
#pragma unroll
            for (int r = 0; r < 4; ++r) {
                float inv = 1.0f / lsum[mt][r];
                int qrow = rowb + mt * 16 + quad * 4 + r;
#pragma unroll
                for (int nt = 0; nt < 4; ++nt)
                    Yatt[((size_t)(bIdx * SEQ + qrow) << 10) + h * 64 + nt * 16 + l16] =
                        f32_to_bf16(o[mt][nt][r] * inv);
            }
    }
}

// ---------------------------------------------------------------- launch
extern "C" void kernel_launch(void* const* d_in, const int* in_sizes, int n_in,
                              void* d_out, int out_size, void* d_ws, size_t ws_size,
                              hipStream_t stream) {
    const float* x = (const float*)d_in[0];
    const float* w_qkv = (const float*)d_in[1];
    const float* b_qkv = (const float*)d_in[2];
    const float* w_proj = (const float*)d_in[3];
    const float* b_proj = (const float*)d_in[4];
    float* out = (float*)d_out;

    char* ws = (char*)d_ws;
    unsigned short* xb     = (unsigned short*)(ws);                       // 16 MB
    unsigned short* wqkvT  = (unsigned short*)(ws + 16777216);            // 6 MB
    unsigned short* wprojT = (unsigned short*)(ws + 23068672);            // 2 MB
    unsigned short* Qb     = (unsigned short*)(ws + 25165824);            // 16 MB
    unsigned short* Kb     = (unsigned short*)(ws + 41943040);            // 16 MB
    unsigned short* Vb     = (unsigned short*)(ws + 58720256);            // 16 MB
    unsigned short* Yatt   = (unsigned short*)(ws + 75497472);            // 16 MB
    unsigned short* Vt     = (unsigned short*)(ws + 92274688);            // 16 MB

    conv_f32_bf16<<<8192, 256, 0, stream>>>(x, xb, (MROWS * DMODEL) / 4);
    transp_conv<<<dim3(96, 32), dim3(32, 8), 0, stream>>>(w_qkv, wqkvT, DMODEL, 3 * DMODEL);
    transp_conv<<<dim3(32, 32), dim3(32, 8), 0, stream>>>(w_proj, wprojT, DMODEL, DMODEL);
    gemm_bt<0><<<dim3(24, 64), 256, 0, stream>>>(xb, wqkvT, b_qkv, nullptr, Qb, Kb, Vb,
                                                 MROWS, 3 * DMODEL, DMODEL);
    transp_bf16_head<<<dim3(2, 64, BATCH * NHEADS), dim3(32, 8), 0, stream>>>(Vb, Vt);
    attn_kernel<<<dim3(64, 8), 256, 0, stream>>>(Qb, Kb, Vt, Yatt);
    gemm_bt<1><<<dim3(8, 64), 256, 0, stream>>>(Yatt, wprojT, b_proj, out, nullptr, nullptr,
                                                nullptr, MROWS, DMODEL, DMODEL);
}

// Round 6
// 248.794 us; speedup vs baseline: 1.1104x; 1.0182x over previous
//
#include <hip/hip_runtime.h>
#include <stdint.h>

#define BATCH 4
#define SEQ 2048
#define DMODEL 1024
#define NHEADS 16
#define HDIM 64
#define MROWS (BATCH * SEQ)   // 8192

typedef float floatx4 __attribute__((ext_vector_type(4)));
typedef __bf16 bf16x8 __attribute__((ext_vector_type(8)));
typedef __bf16 bf16x4 __attribute__((ext_vector_type(4)));
typedef short short8 __attribute__((ext_vector_type(8)));

__device__ __forceinline__ unsigned short f32_to_bf16(float f) {
    union { float f; unsigned int u; } c; c.f = f;
    unsigned int u = c.u;
    unsigned int r = (u + 0x7FFFu + ((u >> 16) & 1u)) >> 16;
    return (unsigned short)r;
}

// async global->LDS 16B per lane (m97 pattern; LDS dest must equal base + lane*16)
__device__ __forceinline__ void async_ld16(const void* g, void* l) {
    __builtin_amdgcn_global_load_lds(
        (const __attribute__((address_space(1))) unsigned int*)g,
        (__attribute__((address_space(3))) unsigned int*)l, 16, 0, 0);
}

// ---------------------------------------------------------------- fused prep
// One kernel replaces conv_f32_bf16 + 2x transp_conv (saves 2 launch gaps).
// gx <  256: x f32->bf16 copy, block id = gx*32+gy (8192 blocks x 256 elems)
// gx <  352: w_qkv [K,N=3072] -> [N,K] bf16 transpose (96 x-blocks)
// gx >= 352: w_proj [K,N=1024] -> [N,K] bf16 transpose (32 x-blocks)
__global__ __launch_bounds__(256) void prep_kernel(
    const float* __restrict__ x, unsigned short* __restrict__ xb,
    const float* __restrict__ w_qkv, unsigned short* __restrict__ wqkvT,
    const float* __restrict__ w_proj, unsigned short* __restrict__ wprojT) {
    const int gx = blockIdx.x, gy = blockIdx.y;
    const int tx = threadIdx.x, ty = threadIdx.y;
    if (gx < 256) {
        int i = (gx * 32 + gy) * 256 + ty * 32 + tx;   // covers exactly MROWS*DMODEL/4
        float4 v = ((const float4*)x)[i];
        ushort4 o;
        o.x = f32_to_bf16(v.x); o.y = f32_to_bf16(v.y);
        o.z = f32_to_bf16(v.z); o.w = f32_to_bf16(v.w);
        ((ushort4*)xb)[i] = o;
        return;  // block-uniform path split
    }
    __shared__ float tile[32][33];
    const float* in; unsigned short* out; int N, bx;
    if (gx < 352) { in = w_qkv; out = wqkvT; N = 3072; bx = (gx - 256) * 32; }
    else          { in = w_proj; out = wprojT; N = 1024; bx = (gx - 352) * 32; }
    const int by = gy * 32;
#pragma unroll
    for (int i = 0; i < 4; ++i)
        tile[ty + i * 8][tx] = in[(size_t)(by + ty + i * 8) * N + bx + tx];
    __syncthreads();
#pragma unroll
    for (int i = 0; i < 4; ++i)
        out[(size_t)(bx + ty + i * 8) * DMODEL + by + tx] = f32_to_bf16(tile[tx][ty + i * 8]);
}

// --------------- per-head bf16 transpose [T,64] -> [64,T], keys PERMUTED within
// each 64-tile: k2 = (k&15)*4 + (k>>4)&3  (must match attn's packed-P layout)
__global__ __launch_bounds__(256) void transp_bf16_head(
    const unsigned short* __restrict__ in, unsigned short* __restrict__ out) {
    __shared__ unsigned short tile[32][33];
    const unsigned short* src = in + (size_t)blockIdx.z * SEQ * HDIM;
    unsigned short* dst = out + (size_t)blockIdx.z * SEQ * HDIM;
    int bx = blockIdx.x * 32;  // d block
    int by = blockIdx.y * 32;  // t block
    int tx = threadIdx.x, ty = threadIdx.y;
#pragma unroll
    for (int i = 0; i < 4; ++i)
        tile[ty + i * 8][tx] = src[(size_t)(by + ty + i * 8) * HDIM + bx + tx];
    __syncthreads();
#pragma unroll
    for (int i = 0; i < 4; ++i) {
        int keyg = by + tx;
        int col2 = (keyg & ~63) | (((keyg & 15) << 2) | ((keyg >> 4) & 3));
        dst[(size_t)(bx + ty + i * 8) * SEQ + col2] = tile[tx][ty + i * 8];
    }
}

// ---------------------------------------------------------------- GEMM (B^T input)
// Round-2 structure: 3-buffer LDS, prefetch distance 2, counted vmcnt + raw
// barrier, plus T1 XCD-aware block swizzle (FETCH 71.7->57.5MB measured R5).
template <int EPI>
__global__ __launch_bounds__(256, 3) void gemm_bt(
    const unsigned short* __restrict__ A, const unsigned short* __restrict__ Bt,
    const float* __restrict__ bias, float* __restrict__ Cout,
    unsigned short* __restrict__ Qo, unsigned short* __restrict__ Ko,
    unsigned short* __restrict__ Vo, int M, int N, int K) {
    __shared__ __align__(16) unsigned short As[3][128 * 32];
    __shared__ __align__(16) unsigned short Bs[3][128 * 32];
    const int tid = threadIdx.x;
    const int lane = tid & 63;
    const int w = tid >> 6;
    const int wm = w & 1, wn = w >> 1;
    const int quad = lane >> 4, l16 = lane & 15;

    // XCD-aware swizzle (contiguous chunk per XCD; bijective since nwg%8==0)
    const int nbx = gridDim.x;
    const int nwg = nbx * gridDim.y;
    const int lin = blockIdx.y * nbx + blockIdx.x;
    const int swz = (lin & 7) * (nwg >> 3) + (lin >> 3);
    const int m0 = (swz / nbx) * 128;
    const int n0 = (swz % nbx) * 128;
    const int fsw = (l16 >> 1) & 3;

    const int idx0 = tid, idx1 = tid + 256;
    const int row0 = idx0 >> 2, row1 = idx1 >> 2;
    const int cg0 = (idx0 & 3) ^ ((row0 >> 1) & 3);
    const int cg1 = (idx1 & 3) ^ ((row1 >> 1) & 3);
    const unsigned short* Ar0 = &A[(size_t)(m0 + row0) * K + cg0 * 8];
    const unsigned short* Ar1 = &A[(size_t)(m0 + row1) * K + cg1 * 8];
    const unsigned short* Br0 = &Bt[(size_t)(n0 + row0) * K + cg0 * 8];
    const unsigned short* Br1 = &Bt[(size_t)(n0 + row1) * K + cg1 * 8];

    floatx4 acc[4][4];
#pragma unroll
    for (int mt = 0; mt < 4; ++mt)
#pragma unroll
        for (int nt = 0; nt < 4; ++nt) acc[mt][nt] = (floatx4){0.f, 0.f, 0.f, 0.f};

    // prologue: tile 0 -> buf 0, tile 1 -> buf 1 (program order = vmcnt drain order)
    async_ld16(Ar0, &As[0][idx0 * 8]);
    async_ld16(Br0, &Bs[0][idx0 * 8]);
    async_ld16(Ar1, &As[0][idx1 * 8]);
    async_ld16(Br1, &Bs[0][idx1 * 8]);
    async_ld16(Ar0 + 32, &As[1][idx0 * 8]);
    async_ld16(Br0 + 32, &Bs[1][idx0 * 8]);
    async_ld16(Ar1 + 32, &As[1][idx1 * 8]);
    async_ld16(Br1 + 32, &Bs[1][idx1 * 8]);

    const int nk = K >> 5;
    int bcur = 0, bpre = 2;
    for (int kt = 0; kt < nk; ++kt) {
        if (kt + 2 < nk)
            asm volatile("s_waitcnt vmcnt(4)" ::: "memory");
        else
            asm volatile("s_waitcnt vmcnt(0)" ::: "memory");
        __builtin_amdgcn_s_barrier();
        asm volatile("" ::: "memory");  // pin prefetch + ds_reads below the barrier

        if (kt + 2 < nk) {  // prefetch distance 2, issued AFTER the barrier
            const int ko = (kt + 2) << 5;
            async_ld16(Ar0 + ko, &As[bpre][idx0 * 8]);
            async_ld16(Br0 + ko, &Bs[bpre][idx0 * 8]);
            async_ld16(Ar1 + ko, &As[bpre][idx1 * 8]);
            async_ld16(Br1 + ko, &Bs[bpre][idx1 * 8]);
        }

        bf16x8 aF[4], bF[4];
#pragma unroll
        for (int mt = 0; mt < 4; ++mt)
            aF[mt] = *(const bf16x8*)&As[bcur][(wm * 64 + mt * 16 + l16) * 32 + (quad ^ fsw) * 8];
#pragma unroll
        for (int nt = 0; nt < 4; ++nt)
            bF[nt] = *(const bf16x8*)&Bs[bcur][(wn * 64 + nt * 16 + l16) * 32 + (quad ^ fsw) * 8];
#pragma unroll
        for (int mt = 0; mt < 4; ++mt)
#pragma unroll
            for (int nt = 0; nt < 4; ++nt)
                acc[mt][nt] = __builtin_amdgcn_mfma_f32_16x16x32_bf16(
                    aF[mt], bF[nt], acc[mt][nt], 0, 0, 0);

        bcur = (bcur == 2) ? 0 : bcur + 1;
        bpre = (bpre == 2) ? 0 : bpre + 1;
    }

#pragma unroll
    for (int mt = 0; mt < 4; ++mt)
#pragma unroll
        for (int nt = 0; nt < 4; ++nt)
#pragma unroll
            for (int r = 0; r < 4; ++r) {
                int m = m0 + wm * 64 + mt * 16 + quad * 4 + r;
                int n = n0 + wn * 64 + nt * 16 + l16;
                float v = acc[mt][nt][r] + bias[n];
                if (EPI == 1) {
                    Cout[(size_t)m * N + n] = v;
                } else {
                    int sel = n >> 10, c = n & 1023;
                    int head = c >> 6, d = c & 63;
                    int bb = m >> 11, t = m & 2047;
                    unsigned short* dst = sel == 0 ? Qo : (sel == 1 ? Ko : Vo);
                    dst[((((size_t)bb * NHEADS + head) * SEQ + t) << 6) + d] = f32_to_bf16(v);
                }
            }
}

// ---------------------------------------------------------------- flash attention v11
// v11: the two mirror strips (sA and 63-sA) now share ONE K/V loop. Previously each
// block ran two sequential loops over the same K/V stream: (2by+2)+(32-2by)=34
// tile-iterations. Merged: kmax = max(2by+2, 32-2by) (avg 25, -26% barrier/stage
// overhead and staging traffic), with wave-uniform per-strip compute skips
// (kb <= lastA / lastB). Skipped tiles were fully-masked (P=0) -> numerics
// identical. Barriers remain block-uniform. Pipeline: 3 buffers, prefetch
// distance 2, counted vmcnt(4), raw barrier (R5 structure).
__device__ __forceinline__ void strip_body(
    int kb, int rowb, int quad, int l16,
    const bf16x8 (&qf)[2][2], const unsigned short* Kb, const unsigned short* Vb,
    unsigned short* Pw, bf16x8 ones, float csc,
    floatx4 (&o)[2][4], floatx4 (&lsum)[2]) {
    // S = Q K^T
    floatx4 s[2][4];
#pragma unroll
    for (int mt = 0; mt < 2; ++mt)
#pragma unroll
        for (int nt = 0; nt < 4; ++nt) s[mt][nt] = (floatx4){0.f, 0.f, 0.f, 0.f};
#pragma unroll
    for (int kk = 0; kk < 2; ++kk) {
        bf16x8 kf[4];
#pragma unroll
        for (int nt = 0; nt < 4; ++nt)
            kf[nt] = *(const bf16x8*)&Kb[(nt * 16 + l16) * 64 +
                                         ((kk * 4 + quad) ^ (l16 & 7)) * 8];
#pragma unroll
        for (int nt = 0; nt < 4; ++nt)
#pragma unroll
            for (int mt = 0; mt < 2; ++mt)
                s[mt][nt] = __builtin_amdgcn_mfma_f32_16x16x32_bf16(
                    qf[mt][kk], kf[nt], s[mt][nt], 0, 0, 0);
    }

    if ((kb * 64 + 63) > rowb) {  // wave-uniform diagonal mask
#pragma unroll
        for (int mt = 0; mt < 2; ++mt)
#pragma unroll
            for (int nt = 0; nt < 4; ++nt)
#pragma unroll
                for (int r = 0; r < 4; ++r) {
                    int key = kb * 64 + nt * 16 + l16;
                    int qrow = rowb + mt * 16 + quad * 4 + r;
                    if (key > qrow) s[mt][nt][r] = -INFINITY;
                }
    }

    // p = exp2(score * 0.125*log2e) == exp(score/8); no max subtraction
#pragma unroll
    for (int mt = 0; mt < 2; ++mt)
#pragma unroll
        for (int nt = 0; nt < 4; ++nt)
#pragma unroll
            for (int r = 0; r < 4; ++r)
                s[mt][nt][r] = __builtin_amdgcn_exp2f(s[mt][nt][r] * csc);

    // P -> per-wave LDS, packed slots k2 = l16*4+nt; swizzled by (prow&14)
#pragma unroll
    for (int mt = 0; mt < 2; ++mt)
#pragma unroll
        for (int r = 0; r < 4; ++r) {
            int prow = mt * 16 + quad * 4 + r;
            int unit = l16 ^ (prow & 14);
            floatx4 t = {s[mt][0][r], s[mt][1][r], s[mt][2][r], s[mt][3][r]};
            bf16x4 pv = __builtin_convertvector(t, bf16x4);
            *(bf16x4*)&Pw[prow * 64 + unit * 4] = pv;
        }

    // O += P V ; l += P 1   (V^T pre-permuted to packed key order)
#pragma unroll
    for (int kk = 0; kk < 2; ++kk) {
        bf16x8 af[2];
#pragma unroll
        for (int mt = 0; mt < 2; ++mt) {
            int prow = mt * 16 + l16;
            int u2 = (kk * 8 + quad * 2) ^ (l16 & 14);
            af[mt] = *(const bf16x8*)&Pw[prow * 64 + u2 * 4];
        }
#pragma unroll
        for (int nt = 0; nt < 4; ++nt) {
            bf16x8 vf = *(const bf16x8*)&Vb[(nt * 16 + l16) * 64 +
                                            ((kk * 4 + quad) ^ (l16 & 7)) * 8];
#pragma unroll
            for (int mt = 0; mt < 2; ++mt)
                o[mt][nt] = __builtin_amdgcn_mfma_f32_16x16x32_bf16(
                    af[mt], vf, o[mt][nt], 0, 0, 0);
        }
#pragma unroll
        for (int mt = 0; mt < 2; ++mt)
            lsum[mt] = __builtin_amdgcn_mfma_f32_16x16x32_bf16(
                af[mt], ones, lsum[mt], 0, 0, 0);
    }
}

__global__ __launch_bounds__(256, 2) void attn_kernel(
    const unsigned short* __restrict__ Qg, const unsigned short* __restrict__ Kg,
    const unsigned short* __restrict__ Vtg, unsigned short* __restrict__ Yatt) {
    __shared__ __align__(16) unsigned short Kb2[3][4096];  // [buf][key][d]   8KB each
    __shared__ __align__(16) unsigned short Vb2[3][4096];  // [buf][d][key~]  8KB each
    __shared__ __align__(16) unsigned short Ps[4][2048];   // per-wave packed P

    const int tid = threadIdx.x;
    const int lane = tid & 63;
    const int w = tid >> 6;
    const int quad = lane >> 4, l16 = lane & 15;
    const int bh = blockIdx.x;           // 0..63 -> XCD bh%8 (L2 locality: all 8
    const int by = blockIdx.y;           //   by-blocks of a bh land on one XCD)
    const int sA = by * 4 + w;           // strip 0..31 (mirror = 63-sA)
    const size_t base = (size_t)bh * SEQ * HDIM;
    const int bIdx = bh >> 4, h = bh & 15;
    unsigned short* Pw = &Ps[w][0];
    const float csc = 0.18033688f;  // 0.125 * log2(e)

    const int lrow = lane >> 3;                 // 0..7 within a DMA instr
    const int lch = (lane & 7) ^ lrow;          // source chunk (store-swizzle ^ row&7)

    short8 osv = {0x3F80, 0x3F80, 0x3F80, 0x3F80, 0x3F80, 0x3F80, 0x3F80, 0x3F80};
    bf16x8 ones = __builtin_bit_cast(bf16x8, osv);

    const int rowbA = sA * 32;
    const int rowbB = (63 - sA) * 32;
    const int tA = 2 * by + 2, tB = 32 - 2 * by;
    const int kmaxB = tA > tB ? tA : tB;        // block-uniform, 18..32
    const int lastA = sA >> 1;                  // strip A computes kb <= lastA
    const int lastB = (2047 - 32 * sA) >> 6;    // strip B computes kb <= lastB

    const unsigned short* Ktg = Kg + base;
    const unsigned short* Vtg_t = Vtg + base;
    const int i0 = w * 2, i1 = w * 2 + 1;
    const int kof0 = (i0 * 8 + lrow) * 64 + lch * 8;
    const int kof1 = (i1 * 8 + lrow) * 64 + lch * 8;
    const size_t vof0 = (size_t)(i0 * 8 + lrow) * SEQ + lch * 8;
    const size_t vof1 = (size_t)(i1 * 8 + lrow) * SEQ + lch * 8;
    const int ld0 = i0 * 512 + lane * 8;
    const int ld1 = i1 * 512 + lane * 8;

    // Q fragments for BOTH strips -> registers
    bf16x8 qfA[2][2], qfB[2][2];
#pragma unroll
    for (int mt = 0; mt < 2; ++mt)
#pragma unroll
        for (int kk = 0; kk < 2; ++kk) {
            qfA[mt][kk] = *(const bf16x8*)&Qg[base + (size_t)(rowbA + mt * 16 + l16) * 64 +
                                              kk * 32 + quad * 8];
            qfB[mt][kk] = *(const bf16x8*)&Qg[base + (size_t)(rowbB + mt * 16 + l16) * 64 +
                                              kk * 32 + quad * 8];
        }
    asm volatile("" ::: "memory");  // keep Q loads above the staging DMAs

    floatx4 lsumA[2], lsumB[2];
    floatx4 oA[2][4], oB[2][4];
#pragma unroll
    for (int mt = 0; mt < 2; ++mt) {
        lsumA[mt] = (floatx4){0.f, 0.f, 0.f, 0.f};
        lsumB[mt] = (floatx4){0.f, 0.f, 0.f, 0.f};
#pragma unroll
        for (int nt = 0; nt < 4; ++nt) {
            oA[mt][nt] = (floatx4){0.f, 0.f, 0.f, 0.f};
            oB[mt][nt] = (floatx4){0.f, 0.f, 0.f, 0.f};
        }
    }

    // prologue: tile 0 -> buf 0, tile 1 -> buf 1 (kmaxB >= 18 always)
    async_ld16(Ktg + kof0, &Kb2[0][ld0]);
    async_ld16(Vtg_t + vof0, &Vb2[0][ld0]);
    async_ld16(Ktg + kof1, &Kb2[0][ld1]);
    async_ld16(Vtg_t + vof1, &Vb2[0][ld1]);
    async_ld16(Ktg + 64 * HDIM + kof0, &Kb2[1][ld0]);
    async_ld16(Vtg_t + 64 + vof0, &Vb2[1][ld0]);
    async_ld16(Ktg + 64 * HDIM + kof1, &Kb2[1][ld1]);
    async_ld16(Vtg_t + 64 + vof1, &Vb2[1][ld1]);

    int bcur = 0, bpre = 2;
    for (int kb = 0; kb < kmaxB; ++kb) {
        if (kb + 2 < kmaxB)
            asm volatile("s_waitcnt vmcnt(4)" ::: "memory");
        else
            asm volatile("s_waitcnt vmcnt(0)" ::: "memory");
        __builtin_amdgcn_s_barrier();
        asm volatile("" ::: "memory");

        if (kb + 2 < kmaxB) {  // prefetch distance 2, AFTER the barrier
            const unsigned short* Kt2 = Ktg + (size_t)(kb + 2) * 64 * HDIM;
            const unsigned short* Vt2 = Vtg_t + (kb + 2) * 64;
            async_ld16(Kt2 + kof0, &Kb2[bpre][ld0]);
            async_ld16(Vt2 + vof0, &Vb2[bpre][ld0]);
            async_ld16(Kt2 + kof1, &Kb2[bpre][ld1]);
            async_ld16(Vt2 + vof1, &Vb2[bpre][ld1]);
        }

        // strip A then strip B share the staged tile; per-wave P-LDS buffer is
        // reused sequentially (compiler orders the intra-wave LDS accesses).
        if (kb <= lastA)
            strip_body(kb, rowbA, quad, l16, qfA, &Kb2[bcur][0], &Vb2[bcur][0],
                       Pw, ones, csc, oA, lsumA);
        if (kb <= lastB)
            strip_body(kb, rowbB, quad, l16, qfB, &Kb2[bcur][0], &Vb2[bcur][0],
                       Pw, ones, csc, oB, lsumB);

        bcur = (bcur == 2) ? 0 : bcur + 1;
        bpre = (bpre == 2) ? 0 : bpre + 1;
    }

    // epilogue: both strips
#pragma unroll
    for (int mt = 0; mt < 2; ++mt)
#pragma unroll
        for (int r = 0; r < 4; ++r) {
            float invA = 1.0f / lsumA[mt][r];
            float invB = 1.0f / lsumB[mt][r];
            int qrowA = rowbA + mt * 16 + quad * 4 + r;
            int qrowB = rowbB + mt * 16 + quad * 4 + r;
#pragma unroll
            for (int nt = 0; nt < 4; ++nt) {
                Yatt[((size_t)(bIdx * SEQ + qrowA) << 10) + h * 64 + nt * 16 + l16] =
                    f32_to_bf16(oA[mt][nt][r] * invA);
                Yatt[((size_t)(bIdx * SEQ + qrowB) << 10) + h * 64 + nt * 16 + l16] =
                    f32_to_bf16(oB[mt][nt][r] * invB);
            }
        }
}

// ---------------------------------------------------------------- launch
extern "C" void kernel_launch(void* const* d_in, const int* in_sizes, int n_in,
                              void* d_out, int out_size, void* d_ws, size_t ws_size,
                              hipStream_t stream) {
    const float* x = (const float*)d_in[0];
    const float* w_qkv = (const float*)d_in[1];
    const float* b_qkv = (const float*)d_in[2];
    const float* w_proj = (const float*)d_in[3];
    const float* b_proj = (const float*)d_in[4];
    float* out = (float*)d_out;

    char* ws = (char*)d_ws;
    unsigned short* xb     = (unsigned short*)(ws);                       // 16 MB
    unsigned short* wqkvT  = (unsigned short*)(ws + 16777216);            // 6 MB
    unsigned short* wprojT = (unsigned short*)(ws + 23068672);            // 2 MB
    unsigned short* Qb     = (unsigned short*)(ws + 25165824);            // 16 MB
    unsigned short* Kb     = (unsigned short*)(ws + 41943040);            // 16 MB
    unsigned short* Vb     = (unsigned short*)(ws + 58720256);            // 16 MB
    unsigned short* Yatt   = (unsigned short*)(ws + 75497472);            // 16 MB
    unsigned short* Vt     = (unsigned short*)(ws + 92274688);            // 16 MB

    prep_kernel<<<dim3(384, 32), dim3(32, 8), 0, stream>>>(x, xb, w_qkv, wqkvT,
                                                           w_proj, wprojT);
    gemm_bt<0><<<dim3(24, 64), 256, 0, stream>>>(xb, wqkvT, b_qkv, nullptr, Qb, Kb, Vb,
                                                 MROWS, 3 * DMODEL, DMODEL);
    transp_bf16_head<<<dim3(2, 64, BATCH * NHEADS), dim3(32, 8), 0, stream>>>(Vb, Vt);
    attn_kernel<<<dim3(64, 8), 256, 0, stream>>>(Qb, Kb, Vt, Yatt);
    gemm_bt<1><<<dim3(8, 64), 256, 0, stream>>>(Yatt, wprojT, b_proj, out, nullptr, nullptr,
                                                nullptr, MROWS, DMODEL, DMODEL);
}